// Round 16
// baseline (396.394 us; speedup 1.0000x reference)
//
#include <hip/hip_runtime.h>

#define NF 16384
#define NB 4096
#define EF 262144
#define EB 65536
#define FBLK 1024   // EF/256
#define BBLK 256    // EB/256
#define CC 32       // cells per Y chunk (2 chunks): 67MB, L3-resident
#define YW (CC * 64)

typedef __attribute__((ext_vector_type(8))) short bf16x8;
typedef __attribute__((ext_vector_type(4))) float f32x4;

__device__ __forceinline__ short f2b(float f) {
  unsigned u = __float_as_uint(f);
  u += 0x7fff + ((u >> 16) & 1);   // RNE
  return (short)(u >> 16);
}
__device__ __forceinline__ unsigned pack2(float lo, float hi) {
  return (unsigned)(unsigned short)f2b(lo) | ((unsigned)(unsigned short)f2b(hi) << 16);
}
__device__ __forceinline__ float b2f_lo(unsigned u) {
  return __uint_as_float(u << 16);
}
__device__ __forceinline__ float b2f_hi(unsigned u) {
  return __uint_as_float(u & 0xffff0000u);
}

// ---------------------------------------------------------------------------
// Basis pass: per edge compute tent-basis cell c00 + bilinear w4, store them,
// and histogram instances into (target, chunk) bins. Cells c00,c00+1 share a
// chunk and c00+8,c00+9 share a chunk -> <=2 atomics per edge.
// ---------------------------------------------------------------------------
__global__ void __launch_bounds__(256) basis_all(
    const int* __restrict__ fi, const int* __restrict__ fj,
    const int* __restrict__ bfi, const int* __restrict__ bb,
    const float* __restrict__ fp, const float* __restrict__ bp,
    const float* __restrict__ supportp,
    unsigned char* __restrict__ fc00, float4* __restrict__ fw4,
    unsigned char* __restrict__ bc00, float4* __restrict__ bw4,
    int* __restrict__ fhist2, int* __restrict__ bhist2) {
  int bid = blockIdx.x;
  bool fluid = bid < FBLK;
  int e = (fluid ? bid : bid - FBLK) * 256 + threadIdx.x;
  int ti = fluid ? fi[e] : bfi[e];
  int si = fluid ? fj[e] : bb[e];
  const float2* pT2 = (const float2*)fp;
  const float2* pS2 = fluid ? (const float2*)fp : (const float2*)bp;
  float sign = fluid ? -1.f : 1.f;
  float inv_sup = 1.0f / supportp[0];
  float2 pt = pT2[ti];
  float2 ps = pS2[si];
  // d = sign*(src-tgt)/support. (-1)*(+0) = -0 preserves reference signed
  // zeros for self-edges (atan2(-0,-0) = -pi).
  float dx = sign * ((ps.x - pt.x) * inv_sup);
  float dy = sign * ((ps.y - pt.y) * inv_sup);
  dx = fminf(fmaxf(dx, -1.f), 1.f);
  dy = fminf(fmaxf(dy, -1.f), 1.f);
  float r = sqrtf(dx * dx + dy * dy + 1e-12f);
  float theta;
  if (dx == 0.0f && dy == 0.0f) {
    float mag = __builtin_signbitf(dx) ? 3.14159265358979323846f : 0.0f;
    theta = __builtin_signbitf(dy) ? -mag : mag;
  } else {
    theta = atan2f(dy, dx);
  }
  float u = 2.f * r - 1.f;
  float v = theta * (1.f / 3.14159265358979323846f);
  float tu = (u + 1.f) * 3.5f;
  float tv = (v + 1.f) * 3.5f;
  int iu = min(max((int)floorf(tu), 0), 6);
  int iv = min(max((int)floorf(tv), 0), 6);
  float wu0 = fmaxf(0.f, 1.f - fabsf(tu - (float)iu));
  float wu1 = fmaxf(0.f, 1.f - fabsf(tu - (float)(iu + 1)));
  float wv0 = fmaxf(0.f, 1.f - fabsf(tv - (float)iv));
  float wv1 = fmaxf(0.f, 1.f - fabsf(tv - (float)(iv + 1)));
  int c00 = iu * 8 + iv;
  float4 w4 = make_float4(wu0 * wv0, wu0 * wv1, wu1 * wv0, wu1 * wv1);
  int chLo = c00 >> 5;           // chunk of c00, c00+1
  int chHi = (c00 + 8) >> 5;     // chunk of c00+8, c00+9
  if (fluid) {
    fc00[e] = (unsigned char)c00; fw4[e] = w4;
    if (chLo == chHi) {
      atomicAdd(fhist2 + ti * 2 + chLo, 4);
    } else {
      atomicAdd(fhist2 + ti * 2 + chLo, 2);
      atomicAdd(fhist2 + ti * 2 + chHi, 2);
    }
  } else {
    bc00[e] = (unsigned char)c00; bw4[e] = w4;
    if (chLo == chHi) {
      atomicAdd(bhist2 + ti * 2 + chLo, 4);
    } else {
      atomicAdd(bhist2 + ti * 2 + chLo, 2);
      atomicAdd(bhist2 + ti * 2 + chHi, 2);
    }
  }
}

// ---------------------------------------------------------------------------
// Exclusive scan over 32768 bins (one block per side).
// ---------------------------------------------------------------------------
__global__ void __launch_bounds__(1024) csr_scan32(const int* __restrict__ fhist,
                                                   const int* __restrict__ bhist,
                                                   int* __restrict__ fstart, int* __restrict__ fcur,
                                                   int* __restrict__ bstart, int* __restrict__ bcur) {
  const int* hist = blockIdx.x ? bhist : fhist;
  int* start = blockIdx.x ? bstart : fstart;
  int* cursor = blockIdx.x ? bcur : fcur;
  __shared__ int wtot[16];
  int t = threadIdx.x;
  int lane = t & 63, wv = t >> 6;
  int base = t * 32;
  int vals[32];
  int s = 0;
#pragma unroll
  for (int k = 0; k < 32; k++) { vals[k] = hist[base + k]; s += vals[k]; }
  int ss = s;
  for (int off = 1; off < 64; off <<= 1) {
    int o = __shfl_up(ss, off, 64);
    if (lane >= off) ss += o;
  }
  if (lane == 63) wtot[wv] = ss;
  __syncthreads();
  if (t < 16) {
    int v = wtot[t];
    int vv = v;
    for (int off = 1; off < 16; off <<= 1) {
      int o = __shfl_up(vv, off, 64);
      if (t >= off) vv += o;
    }
    wtot[t] = vv - v;
  }
  __syncthreads();
  int run = ss - s + wtot[wv];
#pragma unroll
  for (int k = 0; k < 32; k++) { start[base + k] = run; cursor[base + k] = run; run += vals[k]; }
  if (t == 1023) start[32768] = run;
}

// ---------------------------------------------------------------------------
// Scatter per-instance payload (src|cell<<14, w) into bucketed CSR order.
// Instance pairs share a bucket -> 2 atomics + 2 uint4 stores per edge.
// ---------------------------------------------------------------------------
__global__ void __launch_bounds__(256) scatter_pay(
    const int* __restrict__ fi, const int* __restrict__ fj,
    const int* __restrict__ bfi, const int* __restrict__ bb,
    const unsigned char* __restrict__ fc00, const float4* __restrict__ fw4,
    const unsigned char* __restrict__ bc00, const float4* __restrict__ bw4,
    int* __restrict__ fcur2, int* __restrict__ bcur2,
    uint2* __restrict__ fpay, uint2* __restrict__ bpay) {
  int bid = blockIdx.x;
  bool fluid = bid < FBLK;
  int e = (fluid ? bid : bid - FBLK) * 256 + threadIdx.x;
  int ti = fluid ? fi[e] : bfi[e];
  unsigned src = (unsigned)(fluid ? fj[e] : bb[e]);
  int c00 = (int)(fluid ? fc00[e] : bc00[e]);
  float4 w4 = fluid ? fw4[e] : bw4[e];
  int* cur2 = fluid ? fcur2 : bcur2;
  uint2* pay = fluid ? fpay : bpay;
  int chLo = c00 >> 5;
  int chHi = (c00 + 8) >> 5;
  int pLo = atomicAdd(cur2 + ti * 2 + chLo, 2);
  pay[pLo]     = make_uint2(src | ((unsigned)c00 << 14), __float_as_uint(w4.x));
  pay[pLo + 1] = make_uint2(src | ((unsigned)(c00 + 1) << 14), __float_as_uint(w4.y));
  int pHi = atomicAdd(cur2 + ti * 2 + chHi, 2);
  pay[pHi]     = make_uint2(src | ((unsigned)(c00 + 8) << 14), __float_as_uint(w4.z));
  pay[pHi + 1] = make_uint2(src | ((unsigned)(c00 + 9) << 14), __float_as_uint(w4.w));
}

// ---------------------------------------------------------------------------
// ALL weight prep in one launch: BT2, BT3, BT4, W0T/W1T transposes.
// ---------------------------------------------------------------------------
__global__ void __launch_bounds__(256) build_weights(
    const float* __restrict__ W2, const float* __restrict__ W3,
    const float* __restrict__ W4, const float* __restrict__ W0,
    const float* __restrict__ W1,
    short* __restrict__ BT2, short* __restrict__ BT3, short* __restrict__ BT4,
    float* __restrict__ W0T, float* __restrict__ W1T) {
  int bid = blockIdx.x;
  if (bid < 1536) {                      // BT2: 393216 elems
    int tid = bid * 256 + threadIdx.x;
    int k = tid % 96, n = tid / 96;
    BT2[tid] = f2b(W2[((size_t)(n >> 6) * 96 + k) * 64 + (n & 63)]);
  } else if (bid < 2560) {               // BT3: 262144 elems
    int tid = (bid - 1536) * 256 + threadIdx.x;
    int k = tid & 63, n = tid >> 6;
    BT3[tid] = f2b(W3[((size_t)(n >> 6) * 64 + k) * 64 + (n & 63)]);
  } else if (bid < 2592) {               // BT4: 8192 elems
    int tid = (bid - 2560) * 256 + threadIdx.x;
    int k = tid & 63, n = tid >> 6;
    BT4[tid] = f2b(W4[((size_t)(n >> 1) * 64 + k) * 2 + (n & 1)]);
  } else {                               // W0T/W1T: 8192 elems each
    int tid = (bid - 2592) * 256 + threadIdx.x;
    int cell = tid >> 7, r = tid & 127;
    int p = r >> 3, k = (r >> 1) & 3, c = r & 1;
    int dst = cell * 128 + p * 8 + k * 2 + c;
    int src = cell * 128 + k * 32 + 2 * p + c;
    W0T[dst] = W0[src];
    W1T[dst] = W1[src];
  }
}

// ---------------------------------------------------------------------------
// Dense MFMA GEMM, LDS-staged tiles.
// ---------------------------------------------------------------------------
template <int K>
__global__ void __launch_bounds__(256, 2) gemm_bf16(
    const short* __restrict__ A, const short* __restrict__ BT,
    short* __restrict__ C, int N) {
  constexpr int KP = K + 8;
  __shared__ __align__(16) short Al[128 * KP];
  __shared__ __align__(16) short Bl[128 * KP];
  int tid = threadIdx.x;
  int lane = tid & 63;
  int w = tid >> 6;
  int m0b = blockIdx.x * 128;
  int n0b = blockIdx.y * 128;
  constexpr int ROWV = K / 8;
  for (int f = tid; f < 128 * ROWV; f += 256) {
    int r = f / ROWV, c = f % ROWV;
    *(float4*)(Al + r * KP + c * 8) = *(const float4*)(A + (size_t)(m0b + r) * K + c * 8);
    *(float4*)(Bl + r * KP + c * 8) = *(const float4*)(BT + (size_t)(n0b + r) * K + c * 8);
  }
  __syncthreads();
  int m0 = (w & 1) * 64;
  int n0 = (w >> 1) * 64;
  int fr = lane & 15;
  int kg = lane >> 4;
  f32x4 acc[4][4] = {};
#pragma unroll
  for (int kc = 0; kc < K; kc += 32) {
    bf16x8 a[4], b[4];
#pragma unroll
    for (int i = 0; i < 4; i++) {
      a[i] = *(const bf16x8*)(Al + (m0 + i * 16 + fr) * KP + kc + kg * 8);
      b[i] = *(const bf16x8*)(Bl + (n0 + i * 16 + fr) * KP + kc + kg * 8);
    }
#pragma unroll
    for (int i = 0; i < 4; i++)
#pragma unroll
      for (int j = 0; j < 4; j++)
        acc[i][j] = __builtin_amdgcn_mfma_f32_16x16x32_bf16(a[i], b[j], acc[i][j], 0, 0, 0);
  }
#pragma unroll
  for (int i = 0; i < 4; i++) {
    int row = m0b + m0 + i * 16 + (lane >> 4) * 4;
#pragma unroll
    for (int j = 0; j < 4; j++) {
      int col = n0b + n0 + j * 16 + (lane & 15);
#pragma unroll
      for (int r = 0; r < 4; r++)
        C[(size_t)(row + r) * N + col] = f2b(acc[i][j][r]);
    }
  }
}

// ---------------------------------------------------------------------------
// Stage 1, per-instance: wave per node; quarter q takes instance base+g*4+q
// (payload broadcast within quarter — no shuffles). Fluid scans both buckets
// contiguously; boundary likewise; lin folded in.
// ---------------------------------------------------------------------------
__global__ void __launch_bounds__(256, 8) b1_stage1(
    const float* __restrict__ ff, const float* __restrict__ bfe,
    const float* __restrict__ fc0,
    const float* __restrict__ W0T, const float* __restrict__ W1T,
    const int* __restrict__ fstart2, const uint2* __restrict__ fpay,
    const int* __restrict__ bstart2, const uint2* __restrict__ bpay,
    float* __restrict__ ans0, short* __restrict__ Xh96) {
  int lane = threadIdx.x & 63;
  int t = __builtin_amdgcn_readfirstlane(blockIdx.x * 4 + (threadIdx.x >> 6));
  int q = lane >> 4;
  int p = lane & 15;

  auto run_side = [&](int lo, int hi, const uint2* pay, const float* xA,
                      const float* WT) -> float2 {
    float2 acc = make_float2(0.f, 0.f);
    for (int base = lo; base < hi; base += 16) {
      float w_[4], xx_[4], xy_[4], xz_[4], xw_[4];
      float4 A_[4], B_[4];
#pragma unroll
      for (int g = 0; g < 4; g++) {
        int myi = base + g * 4 + q;
        bool act = myi < hi;
        uint2 pl = act ? pay[myi] : make_uint2(0u, 0u);
        int src = pl.x & 16383;
        int cell = (int)(pl.x >> 14);
        w_[g] = __uint_as_float(pl.y);
        float4 xv = *(const float4*)(xA + (size_t)src * 4);
        xx_[g] = xv.x; xy_[g] = xv.y; xz_[g] = xv.z; xw_[g] = xv.w;
        const float4* Wt = (const float4*)(WT + cell * 128 + p * 8);
        A_[g] = Wt[0];
        B_[g] = Wt[1];
      }
#pragma unroll
      for (int g = 0; g < 4; g++) {
        acc.x = fmaf(w_[g],
                     xx_[g] * A_[g].x + xy_[g] * A_[g].z + xz_[g] * B_[g].x + xw_[g] * B_[g].z,
                     acc.x);
        acc.y = fmaf(w_[g],
                     xx_[g] * A_[g].y + xy_[g] * A_[g].w + xz_[g] * B_[g].y + xw_[g] * B_[g].w,
                     acc.y);
      }
    }
    return acc;
  };

  int flo = __builtin_amdgcn_readfirstlane(fstart2[2 * t]);
  int fhi = __builtin_amdgcn_readfirstlane(fstart2[2 * t + 2]);
  int blo = __builtin_amdgcn_readfirstlane(bstart2[2 * t]);
  int bhi = __builtin_amdgcn_readfirstlane(bstart2[2 * t + 2]);
  float2 fa = run_side(flo, fhi, fpay, ff, W0T);
  float2 ba = run_side(blo, bhi, bpay, bfe, W1T);

  fa.x += __shfl_xor(fa.x, 16, 64); fa.y += __shfl_xor(fa.y, 16, 64);
  fa.x += __shfl_xor(fa.x, 32, 64); fa.y += __shfl_xor(fa.y, 32, 64);
  ba.x += __shfl_xor(ba.x, 16, 64); ba.y += __shfl_xor(ba.y, 16, 64);
  ba.x += __shfl_xor(ba.x, 32, 64); ba.y += __shfl_xor(ba.y, 32, 64);
  if (lane < 16) {
    fa.x = fmaxf(fa.x, 0.f); fa.y = fmaxf(fa.y, 0.f);
    *(float2*)(ans0 + (size_t)t * 96 + 32 + 2 * p) = fa;
    *(unsigned*)(Xh96 + (size_t)t * 96 + 32 + 2 * p) = pack2(fa.x, fa.y);
  } else if (lane < 32) {
    ba.x = fmaxf(ba.x, 0.f); ba.y = fmaxf(ba.y, 0.f);
    *(float2*)(ans0 + (size_t)t * 96 + 64 + 2 * p) = ba;
    *(unsigned*)(Xh96 + (size_t)t * 96 + 64 + 2 * p) = pack2(ba.x, ba.y);
  } else if (lane < 48) {
    float4 fv = *(const float4*)(ff + (size_t)t * 4);
    float l0 = fv.x * fc0[2 * p] + fv.y * fc0[32 + 2 * p] +
               fv.z * fc0[64 + 2 * p] + fv.w * fc0[96 + 2 * p];
    float l1 = fv.x * fc0[2 * p + 1] + fv.y * fc0[32 + 2 * p + 1] +
               fv.z * fc0[64 + 2 * p + 1] + fv.w * fc0[96 + 2 * p + 1];
    l0 = fmaxf(l0, 0.f); l1 = fmaxf(l1, 0.f);
    *(float2*)(ans0 + (size_t)t * 96 + 2 * p) = make_float2(l0, l1);
    *(unsigned*)(Xh96 + (size_t)t * 96 + 2 * p) = pack2(l0, l1);
  }
}

// ---------------------------------------------------------------------------
// Phase B stages 2/3, per-instance bucketed: pass r scans bucket r only; all
// cells guaranteed in-window; quarter q = instance; no shuffles; 8 gathers in
// flight.
// ---------------------------------------------------------------------------
template <int CIN, int RESID, int WBF16>
__global__ void __launch_bounds__(256, 4) b23(
    const float* __restrict__ xin, const float* __restrict__ fc,
    const int* __restrict__ fstart2, const uint2* __restrict__ fpay,
    const short* __restrict__ Y, const float* __restrict__ resid,
    float* __restrict__ dest, short* __restrict__ Xh64,
    int c0, int r, int init, int fin) {
  int lane = threadIdx.x & 63;
  int t = __builtin_amdgcn_readfirstlane(blockIdx.x * 4 + (threadIdx.x >> 6));
  int q = lane >> 4;
  int sub = lane & 15;
  float a0 = 0.f, a1 = 0.f, a2 = 0.f, a3 = 0.f;
  if (init) {
    const float* xr = xin + (size_t)t * CIN;
#pragma unroll
    for (int kk = 0; kk < CIN / 4; kk++) {
      int k = q * (CIN / 4) + kk;
      float xv = xr[k];
      float4 fv = *(const float4*)(fc + (size_t)k * 64 + 4 * sub);
      a0 = fmaf(xv, fv.x, a0);
      a1 = fmaf(xv, fv.y, a1);
      a2 = fmaf(xv, fv.z, a2);
      a3 = fmaf(xv, fv.w, a3);
    }
  }
  int lo = __builtin_amdgcn_readfirstlane(fstart2[2 * t + r]);
  int hi = __builtin_amdgcn_readfirstlane(fstart2[2 * t + r + 1]);
  for (int base = lo; base < hi; base += 32) {
    float w_[8];
    uint2 r_[8];
#pragma unroll
    for (int g = 0; g < 8; g++) {
      int myi = base + g * 4 + q;
      bool act = myi < hi;
      uint2 pl = act ? fpay[myi] : make_uint2(0u, 0u);
      int src = pl.x & 16383;
      int cell = (int)(pl.x >> 14) - c0;
      w_[g] = __uint_as_float(pl.y);
      r_[g] = make_uint2(0u, 0u);
      if (act) r_[g] = *(const uint2*)(Y + (size_t)src * YW + cell * 64 + 4 * sub);
    }
#pragma unroll
    for (int g = 0; g < 8; g++) {
      a0 = fmaf(w_[g], b2f_lo(r_[g].x), a0);
      a1 = fmaf(w_[g], b2f_hi(r_[g].x), a1);
      a2 = fmaf(w_[g], b2f_lo(r_[g].y), a2);
      a3 = fmaf(w_[g], b2f_hi(r_[g].y), a3);
    }
  }
  a0 += __shfl_xor(a0, 16, 64); a1 += __shfl_xor(a1, 16, 64);
  a2 += __shfl_xor(a2, 16, 64); a3 += __shfl_xor(a3, 16, 64);
  a0 += __shfl_xor(a0, 32, 64); a1 += __shfl_xor(a1, 32, 64);
  a2 += __shfl_xor(a2, 32, 64); a3 += __shfl_xor(a3, 32, 64);
  if (lane < 16) {
    float4* dst = (float4*)(dest + (size_t)t * 64 + 4 * sub);
    if (!init) {
      float4 d = *dst;
      a0 += d.x; a1 += d.y; a2 += d.z; a3 += d.w;
    }
    if (RESID && init) {
      float4 rd = *(const float4*)(resid + (size_t)t * 64 + 4 * sub);
      a0 += rd.x; a1 += rd.y; a2 += rd.z; a3 += rd.w;
    }
    if (fin) {
      a0 = fmaxf(a0, 0.f); a1 = fmaxf(a1, 0.f);
      a2 = fmaxf(a2, 0.f); a3 = fmaxf(a3, 0.f);
    }
    *dst = make_float4(a0, a1, a2, a3);
    if (WBF16 && fin) {
      uint2 pkd = make_uint2(pack2(a0, a1), pack2(a2, a3));
      *(uint2*)(Xh64 + (size_t)t * 64 + 4 * sub) = pkd;
    }
  }
}

// ---------------------------------------------------------------------------
// Phase B stage 4, per-instance: lane = instance slot; Y4h full (64 cells).
// ---------------------------------------------------------------------------
__global__ void __launch_bounds__(256, 8) b4_stage4(
    const float* __restrict__ ans2, const float* __restrict__ fc3,
    const int* __restrict__ fstart2, const uint2* __restrict__ fpay,
    const short* __restrict__ Y4h, float* __restrict__ outp) {
  int lane = threadIdx.x & 63;
  int t = blockIdx.x * 4 + (threadIdx.x >> 6);
  int lo = fstart2[2 * t], hi = fstart2[2 * t + 2];
  float m0 = 0.f, m1 = 0.f;
  for (int i = lo + lane; i < hi; i += 64) {
    uint2 pl = fpay[i];
    int src = pl.x & 16383;
    int cell = (int)(pl.x >> 14);
    float w = __uint_as_float(pl.y);
    unsigned mm = *(const unsigned*)(Y4h + (size_t)src * 128 + cell * 2);
    m0 = fmaf(w, b2f_lo(mm), m0);
    m1 = fmaf(w, b2f_hi(mm), m1);
  }
  {
    float a = ans2[(size_t)t * 64 + lane];
    m0 += a * fc3[lane * 2 + 0];
    m1 += a * fc3[lane * 2 + 1];
  }
#pragma unroll
  for (int off = 32; off > 0; off >>= 1) {
    m0 += __shfl_xor(m0, off, 64);
    m1 += __shfl_xor(m1, off, 64);
  }
  if (lane == 0) {
    outp[t * 2] = m0;
    outp[t * 2 + 1] = m1;
  }
}

// ---------------------------------------------------------------------------
extern "C" void kernel_launch(void* const* d_in, const int* in_sizes, int n_in,
                              void* d_out, int out_size, void* d_ws, size_t ws_size,
                              hipStream_t stream) {
  const float* fp  = (const float*)d_in[0];
  const float* bp  = (const float*)d_in[1];
  const float* ff  = (const float*)d_in[2];
  const float* bfe = (const float*)d_in[3];
  const float* sup = (const float*)d_in[4];
  const int* fi  = (const int*)d_in[5];
  const int* fj  = (const int*)d_in[6];
  const int* bfi = (const int*)d_in[7];
  const int* bb  = (const int*)d_in[8];
  const float* W0 = (const float*)d_in[9];
  const float* W1 = (const float*)d_in[10];
  const float* W2 = (const float*)d_in[11];
  const float* W3 = (const float*)d_in[12];
  const float* W4 = (const float*)d_in[13];
  const float* fc0 = (const float*)d_in[14];
  const float* fc1 = (const float*)d_in[15];
  const float* fc2 = (const float*)d_in[16];
  const float* fc3 = (const float*)d_in[17];
  float* out = (float*)d_out;

  char* w = (char*)d_ws;
  size_t off = 0;
  auto alloc = [&](size_t bytes) {
    char* p = w + off;
    off += (bytes + 255) & ~size_t(255);
    return p;
  };
  float* ans0   = (float*)alloc((size_t)NF * 96 * 4);
  float* ans1   = (float*)alloc((size_t)NF * 64 * 4);
  float* ans2   = (float*)alloc((size_t)NF * 64 * 4);
  int* fhist2  = (int*)alloc((size_t)NF * 2 * 4);
  int* bhist2  = (int*)alloc((size_t)NF * 2 * 4);   // adjacent: one memset
  int* fstart2 = (int*)alloc((size_t)(NF * 2 + 1) * 4);
  int* fcur2   = (int*)alloc((size_t)NF * 2 * 4);
  int* bstart2 = (int*)alloc((size_t)(NF * 2 + 1) * 4);
  int* bcur2   = (int*)alloc((size_t)NF * 2 * 4);
  unsigned char* fc00 = (unsigned char*)alloc((size_t)EF);
  float4* fw4  = (float4*)alloc((size_t)EF * 16);
  unsigned char* bc00 = (unsigned char*)alloc((size_t)EB);
  float4* bw4  = (float4*)alloc((size_t)EB * 16);
  uint2* fpay  = (uint2*)alloc((size_t)EF * 4 * 8);
  uint2* bpay  = (uint2*)alloc((size_t)EB * 4 * 8);
  short* Xh96  = (short*)alloc((size_t)NF * 96 * 2);
  short* Xh64  = (short*)alloc((size_t)NF * 64 * 2);
  short* Xh64b = (short*)alloc((size_t)NF * 64 * 2);
  short* BT2 = (short*)alloc((size_t)4096 * 96 * 2);
  short* BT3 = (short*)alloc((size_t)4096 * 64 * 2);
  short* BT4 = (short*)alloc((size_t)128 * 64 * 2);
  float* W0T = (float*)alloc((size_t)8192 * 4);
  float* W1T = (float*)alloc((size_t)8192 * 4);
  short* Y   = (short*)alloc((size_t)NF * YW * 2);  // 67MB chunk, L3-resident
  short* Y4h = Y;                                   // [NF][128] bf16 (reuses Y)

  hipMemsetAsync(fhist2, 0, (size_t)NF * 4 * 4, stream);

  build_weights<<<2624, 256, 0, stream>>>(W2, W3, W4, W0, W1, BT2, BT3, BT4, W0T, W1T);
  basis_all<<<FBLK + BBLK, 256, 0, stream>>>(fi, fj, bfi, bb, fp, bp, sup,
                                             fc00, fw4, bc00, bw4, fhist2, bhist2);
  csr_scan32<<<2, 1024, 0, stream>>>(fhist2, bhist2, fstart2, fcur2, bstart2, bcur2);
  scatter_pay<<<FBLK + BBLK, 256, 0, stream>>>(fi, fj, bfi, bb, fc00, fw4, bc00, bw4,
                                               fcur2, bcur2, fpay, bpay);

  // Stage 1: per-instance fused. Emits ans0 + bf16 Xh96.
  b1_stage1<<<NF / 4, 256, 0, stream>>>(ff, bfe, fc0, W0T, W1T,
                                        fstart2, fpay, bstart2, bpay, ans0, Xh96);
  // Stage 2: per-chunk MFMA GEMM + bucketed gather. Emits ans1 + bf16 Xh64.
  for (int r = 0; r < 2; r++) {
    int c0 = r * CC;
    gemm_bf16<96><<<dim3(NF / 128, YW / 128), 256, 0, stream>>>(
        Xh96, BT2 + (size_t)c0 * 64 * 96, Y, YW);
    b23<96, 0, 1><<<NF / 4, 256, 0, stream>>>(ans0, fc1, fstart2, fpay,
                                              Y, nullptr, ans1, Xh64,
                                              c0, r, r == 0, r == 1);
  }
  // Stage 3: emits ans2 + bf16 Xh64b.
  for (int r = 0; r < 2; r++) {
    int c0 = r * CC;
    gemm_bf16<64><<<dim3(NF / 128, YW / 128), 256, 0, stream>>>(
        Xh64, BT3 + (size_t)c0 * 64 * 64, Y, YW);
    b23<64, 1, 1><<<NF / 4, 256, 0, stream>>>(ans1, fc2, fstart2, fpay,
                                              Y, ans1, ans2, Xh64b,
                                              c0, r, r == 0, r == 1);
  }
  // Stage 4: W4 conv as one MFMA GEMM [NF x 64] @ [64 x 128], then gather.
  gemm_bf16<64><<<dim3(NF / 128, 1), 256, 0, stream>>>(Xh64b, BT4, Y4h, 128);
  b4_stage4<<<NF / 4, 256, 0, stream>>>(ans2, fc3, fstart2, fpay, Y4h, out);
}

// Round 17
// 313.724 us; speedup vs baseline: 1.2635x; 1.2635x over previous
//
#include <hip/hip_runtime.h>

#define NF 16384
#define NB 4096
#define EF 262144
#define EB 65536
#define FBLK 1024   // EF/256
#define BBLK 256    // EB/256

typedef __attribute__((ext_vector_type(8))) short bf16x8;
typedef __attribute__((ext_vector_type(4))) float f32x4;

__device__ __forceinline__ short f2b(float f) {
  unsigned u = __float_as_uint(f);
  u += 0x7fff + ((u >> 16) & 1);   // RNE
  return (short)(u >> 16);
}
__device__ __forceinline__ unsigned pack2(float lo, float hi) {
  return (unsigned)(unsigned short)f2b(lo) | ((unsigned)(unsigned short)f2b(hi) << 16);
}
__device__ __forceinline__ float b2f_lo(unsigned u) {
  return __uint_as_float(u << 16);
}
__device__ __forceinline__ float b2f_hi(unsigned u) {
  return __uint_as_float(u & 0xffff0000u);
}

// ---------------------------------------------------------------------------
// Target CSR: histogram (merged fluid+boundary).
// ---------------------------------------------------------------------------
__global__ void __launch_bounds__(256) dual_hist(const int* __restrict__ fi,
                                                 const int* __restrict__ bfi,
                                                 int* __restrict__ fhist,
                                                 int* __restrict__ bhist) {
  int bid = blockIdx.x;
  if (bid < FBLK) {
    int e = bid * 256 + threadIdx.x;
    atomicAdd(fhist + fi[e], 1);
  } else {
    int e = (bid - FBLK) * 256 + threadIdx.x;
    atomicAdd(bhist + bfi[e], 1);
  }
}

__global__ void __launch_bounds__(1024) csr_scan2(const int* __restrict__ fhist,
                                                  const int* __restrict__ bhist,
                                                  int* __restrict__ fstart, int* __restrict__ fcur,
                                                  int* __restrict__ bstart, int* __restrict__ bcur) {
  const int* hist = blockIdx.x ? bhist : fhist;
  int* start = blockIdx.x ? bstart : fstart;
  int* cursor = blockIdx.x ? bcur : fcur;
  __shared__ int wtot[16];
  int t = threadIdx.x;
  int lane = t & 63, wv = t >> 6;
  int base = t * 16;
  int vals[16];
  int s = 0;
#pragma unroll
  for (int k = 0; k < 16; k++) { vals[k] = hist[base + k]; s += vals[k]; }
  int ss = s;
  for (int off = 1; off < 64; off <<= 1) {
    int o = __shfl_up(ss, off, 64);
    if (lane >= off) ss += o;
  }
  if (lane == 63) wtot[wv] = ss;
  __syncthreads();
  if (t < 16) {
    int v = wtot[t];
    int vv = v;
    for (int off = 1; off < 16; off <<= 1) {
      int o = __shfl_up(vv, off, 64);
      if (t >= off) vv += o;
    }
    wtot[t] = vv - v;
  }
  __syncthreads();
  int run = ss - s + wtot[wv];
#pragma unroll
  for (int k = 0; k < 16; k++) { start[base + k] = run; cursor[base + k] = run; run += vals[k]; }
  if (t == 1023) start[16384] = run;
}

// ---------------------------------------------------------------------------
// Merged scatter + payload + tent-basis.
// ---------------------------------------------------------------------------
__global__ void __launch_bounds__(256) dual_scatter_payload(
    const int* __restrict__ fi, const int* __restrict__ fj,
    const int* __restrict__ bfi, const int* __restrict__ bb,
    const float* __restrict__ fp, const float* __restrict__ bp,
    const float* __restrict__ supportp,
    int* __restrict__ fcur, int* __restrict__ bcur,
    unsigned* __restrict__ fpk, float4* __restrict__ fwt,
    unsigned* __restrict__ bpk, float4* __restrict__ bwt) {
  int bid = blockIdx.x;
  bool fluid = bid < FBLK;
  int e = (fluid ? bid : bid - FBLK) * 256 + threadIdx.x;
  int ti = fluid ? fi[e] : bfi[e];
  int si = fluid ? fj[e] : bb[e];
  const float2* pT2 = (const float2*)fp;
  const float2* pS2 = fluid ? (const float2*)fp : (const float2*)bp;
  float sign = fluid ? -1.f : 1.f;
  float inv_sup = 1.0f / supportp[0];
  float2 pt = pT2[ti];
  float2 ps = pS2[si];
  // d = sign*(src-tgt)/support. (-1)*(+0) = -0 preserves reference signed
  // zeros for self-edges (atan2(-0,-0) = -pi).
  float dx = sign * ((ps.x - pt.x) * inv_sup);
  float dy = sign * ((ps.y - pt.y) * inv_sup);
  dx = fminf(fmaxf(dx, -1.f), 1.f);
  dy = fminf(fmaxf(dy, -1.f), 1.f);
  float r = sqrtf(dx * dx + dy * dy + 1e-12f);
  float theta;
  if (dx == 0.0f && dy == 0.0f) {
    float mag = __builtin_signbitf(dx) ? 3.14159265358979323846f : 0.0f;
    theta = __builtin_signbitf(dy) ? -mag : mag;
  } else {
    theta = atan2f(dy, dx);
  }
  float u = 2.f * r - 1.f;
  float v = theta * (1.f / 3.14159265358979323846f);
  float tu = (u + 1.f) * 3.5f;
  float tv = (v + 1.f) * 3.5f;
  int iu = min(max((int)floorf(tu), 0), 6);
  int iv = min(max((int)floorf(tv), 0), 6);
  float wu0 = fmaxf(0.f, 1.f - fabsf(tu - (float)iu));
  float wu1 = fmaxf(0.f, 1.f - fabsf(tu - (float)(iu + 1)));
  float wv0 = fmaxf(0.f, 1.f - fabsf(tv - (float)iv));
  float wv1 = fmaxf(0.f, 1.f - fabsf(tv - (float)(iv + 1)));
  unsigned pk = (unsigned)si | ((unsigned)(iu * 8 + iv) << 14);
  float4 w4 = make_float4(wu0 * wv0, wu0 * wv1, wu1 * wv0, wu1 * wv1);
  if (fluid) {
    int p = atomicAdd(fcur + ti, 1);
    fpk[p] = pk; fwt[p] = w4;
  } else {
    int p = atomicAdd(bcur + ti, 1);
    bpk[p] = pk; bwt[p] = w4;
  }
}

// ---------------------------------------------------------------------------
// ALL weight prep in one launch: BT2 (4096x96), BT3 (4096x64), BT4 (128x64),
// W0T/W1T transposes.
// ---------------------------------------------------------------------------
__global__ void __launch_bounds__(256) build_weights(
    const float* __restrict__ W2, const float* __restrict__ W3,
    const float* __restrict__ W4, const float* __restrict__ W0,
    const float* __restrict__ W1,
    short* __restrict__ BT2, short* __restrict__ BT3, short* __restrict__ BT4,
    float* __restrict__ W0T, float* __restrict__ W1T) {
  int bid = blockIdx.x;
  if (bid < 1536) {                      // BT2: 393216 elems
    int tid = bid * 256 + threadIdx.x;
    int k = tid % 96, n = tid / 96;
    BT2[tid] = f2b(W2[((size_t)(n >> 6) * 96 + k) * 64 + (n & 63)]);
  } else if (bid < 2560) {               // BT3: 262144 elems
    int tid = (bid - 1536) * 256 + threadIdx.x;
    int k = tid & 63, n = tid >> 6;
    BT3[tid] = f2b(W3[((size_t)(n >> 6) * 64 + k) * 64 + (n & 63)]);
  } else if (bid < 2592) {               // BT4: 8192 elems
    int tid = (bid - 2560) * 256 + threadIdx.x;
    int k = tid & 63, n = tid >> 6;
    BT4[tid] = f2b(W4[((size_t)(n >> 1) * 64 + k) * 2 + (n & 1)]);
  } else {                               // W0T/W1T: 8192 elems each
    int tid = (bid - 2592) * 256 + threadIdx.x;
    int cell = tid >> 7, r = tid & 127;
    int p = r >> 3, k = (r >> 1) & 3, c = r & 1;
    int dst = cell * 128 + p * 8 + k * 2 + c;
    int src = cell * 128 + k * 32 + 2 * p + c;
    W0T[dst] = W0[src];
    W1T[dst] = W1[src];
  }
}

// ---------------------------------------------------------------------------
// Dense MFMA GEMM, LDS-staged tiles (conflict-free padded rows, 16B aligned).
// ---------------------------------------------------------------------------
template <int K>
__global__ void __launch_bounds__(256, 2) gemm_bf16(
    const short* __restrict__ A, const short* __restrict__ BT,
    short* __restrict__ C, int N) {
  constexpr int KP = K + 8;
  __shared__ __align__(16) short Al[128 * KP];
  __shared__ __align__(16) short Bl[128 * KP];
  int tid = threadIdx.x;
  int lane = tid & 63;
  int w = tid >> 6;
  int m0b = blockIdx.x * 128;
  int n0b = blockIdx.y * 128;
  constexpr int ROWV = K / 8;
  for (int f = tid; f < 128 * ROWV; f += 256) {
    int r = f / ROWV, c = f % ROWV;
    *(float4*)(Al + r * KP + c * 8) = *(const float4*)(A + (size_t)(m0b + r) * K + c * 8);
    *(float4*)(Bl + r * KP + c * 8) = *(const float4*)(BT + (size_t)(n0b + r) * K + c * 8);
  }
  __syncthreads();
  int m0 = (w & 1) * 64;
  int n0 = (w >> 1) * 64;
  int fr = lane & 15;
  int kg = lane >> 4;
  f32x4 acc[4][4] = {};
#pragma unroll
  for (int kc = 0; kc < K; kc += 32) {
    bf16x8 a[4], b[4];
#pragma unroll
    for (int i = 0; i < 4; i++) {
      a[i] = *(const bf16x8*)(Al + (m0 + i * 16 + fr) * KP + kc + kg * 8);
      b[i] = *(const bf16x8*)(Bl + (n0 + i * 16 + fr) * KP + kc + kg * 8);
    }
#pragma unroll
    for (int i = 0; i < 4; i++)
#pragma unroll
      for (int j = 0; j < 4; j++)
        acc[i][j] = __builtin_amdgcn_mfma_f32_16x16x32_bf16(a[i], b[j], acc[i][j], 0, 0, 0);
  }
#pragma unroll
  for (int i = 0; i < 4; i++) {
    int row = m0b + m0 + i * 16 + (lane >> 4) * 4;
#pragma unroll
    for (int j = 0; j < 4; j++) {
      int col = n0b + n0 + j * 16 + (lane & 15);
#pragma unroll
      for (int r = 0; r < 4; r++)
        C[(size_t)(row + r) * N + col] = f2b(acc[i][j][r]);
    }
  }
}

// ---------------------------------------------------------------------------
// Stage 1, lane-parallel payload + 4-edge unrolled broadcast loop (W0T/W1T).
// ---------------------------------------------------------------------------
__global__ void __launch_bounds__(256, 8) b1_stage1(
    const float* __restrict__ ff, const float* __restrict__ bfe,
    const float* __restrict__ fc0,
    const float* __restrict__ W0T, const float* __restrict__ W1T,
    const int* __restrict__ ftstart, const unsigned* __restrict__ fpk,
    const float4* __restrict__ fwt,
    const int* __restrict__ btstart, const unsigned* __restrict__ bpk,
    const float4* __restrict__ bwt,
    float* __restrict__ ans0, short* __restrict__ Xh96) {
  int lane = threadIdx.x & 63;
  int t = __builtin_amdgcn_readfirstlane(blockIdx.x * 4 + (threadIdx.x >> 6));
  int q = lane >> 4;
  int p = lane & 15;
  int cofs = (q & 1) + (q >> 1) * 8;

  auto run_side = [&](const int* st, const unsigned* pkA, const float4* wtA,
                      const float* xA, const float* WT) -> float2 {
    float2 acc = make_float2(0.f, 0.f);
    int s = __builtin_amdgcn_readfirstlane(st[t]);
    int e1 = __builtin_amdgcn_readfirstlane(st[t + 1]);
    for (int base = s; base < e1; base += 64) {
      int Ln = min(64, e1 - base);
      unsigned mypk = 0;
      float4 myw = make_float4(0.f, 0.f, 0.f, 0.f);
      float4 myx = make_float4(0.f, 0.f, 0.f, 0.f);
      if (lane < Ln) {
        mypk = pkA[base + lane];
        myw = wtA[base + lane];
        myx = *(const float4*)(xA + (size_t)(mypk & 16383) * 4);
      }
      int j = 0;
      for (; j + 3 < Ln; j += 4) {
        unsigned pk_[4];
        float wq_[4], xx_[4], xy_[4], xz_[4], xw_[4];
#pragma unroll
        for (int u = 0; u < 4; u++) {
          pk_[u] = __shfl(mypk, j + u, 64);
          float wx = __shfl(myw.x, j + u, 64), wy = __shfl(myw.y, j + u, 64);
          float wz = __shfl(myw.z, j + u, 64), ww = __shfl(myw.w, j + u, 64);
          wq_[u] = (q == 0) ? wx : (q == 1) ? wy : (q == 2) ? wz : ww;
          xx_[u] = __shfl(myx.x, j + u, 64);
          xy_[u] = __shfl(myx.y, j + u, 64);
          xz_[u] = __shfl(myx.z, j + u, 64);
          xw_[u] = __shfl(myx.w, j + u, 64);
        }
        float4 A_[4], B_[4];
#pragma unroll
        for (int u = 0; u < 4; u++) {
          int cell = (int)(pk_[u] >> 14) + cofs;
          const float4* Wt = (const float4*)(WT + cell * 128 + p * 8);
          A_[u] = Wt[0];
          B_[u] = Wt[1];
        }
#pragma unroll
        for (int u = 0; u < 4; u++) {
          acc.x = fmaf(wq_[u],
                       xx_[u] * A_[u].x + xy_[u] * A_[u].z + xz_[u] * B_[u].x + xw_[u] * B_[u].z,
                       acc.x);
          acc.y = fmaf(wq_[u],
                       xx_[u] * A_[u].y + xy_[u] * A_[u].w + xz_[u] * B_[u].y + xw_[u] * B_[u].w,
                       acc.y);
        }
      }
      for (; j < Ln; j++) {
        unsigned pk = __shfl(mypk, j, 64);
        float wx = __shfl(myw.x, j, 64), wy = __shfl(myw.y, j, 64);
        float wz = __shfl(myw.z, j, 64), ww = __shfl(myw.w, j, 64);
        float xx = __shfl(myx.x, j, 64), xy = __shfl(myx.y, j, 64);
        float xz = __shfl(myx.z, j, 64), xw = __shfl(myx.w, j, 64);
        float wq = (q == 0) ? wx : (q == 1) ? wy : (q == 2) ? wz : ww;
        int cell = (int)(pk >> 14) + cofs;
        const float4* Wt = (const float4*)(WT + cell * 128 + p * 8);
        float4 A = Wt[0], B = Wt[1];
        acc.x = fmaf(wq, xx * A.x + xy * A.z + xz * B.x + xw * B.z, acc.x);
        acc.y = fmaf(wq, xx * A.y + xy * A.w + xz * B.y + xw * B.w, acc.y);
      }
    }
    return acc;
  };

  float2 fa = run_side(ftstart, fpk, fwt, ff, W0T);
  float2 ba = run_side(btstart, bpk, bwt, bfe, W1T);

  fa.x += __shfl_xor(fa.x, 16, 64); fa.y += __shfl_xor(fa.y, 16, 64);
  fa.x += __shfl_xor(fa.x, 32, 64); fa.y += __shfl_xor(fa.y, 32, 64);
  ba.x += __shfl_xor(ba.x, 16, 64); ba.y += __shfl_xor(ba.y, 16, 64);
  ba.x += __shfl_xor(ba.x, 32, 64); ba.y += __shfl_xor(ba.y, 32, 64);
  if (lane < 16) {
    fa.x = fmaxf(fa.x, 0.f); fa.y = fmaxf(fa.y, 0.f);
    *(float2*)(ans0 + (size_t)t * 96 + 32 + 2 * p) = fa;
    *(unsigned*)(Xh96 + (size_t)t * 96 + 32 + 2 * p) = pack2(fa.x, fa.y);
  } else if (lane < 32) {
    ba.x = fmaxf(ba.x, 0.f); ba.y = fmaxf(ba.y, 0.f);
    *(float2*)(ans0 + (size_t)t * 96 + 64 + 2 * p) = ba;
    *(unsigned*)(Xh96 + (size_t)t * 96 + 64 + 2 * p) = pack2(ba.x, ba.y);
  } else if (lane < 48) {
    float4 fv = *(const float4*)(ff + (size_t)t * 4);
    float l0 = fv.x * fc0[2 * p] + fv.y * fc0[32 + 2 * p] +
               fv.z * fc0[64 + 2 * p] + fv.w * fc0[96 + 2 * p];
    float l1 = fv.x * fc0[2 * p + 1] + fv.y * fc0[32 + 2 * p + 1] +
               fv.z * fc0[64 + 2 * p + 1] + fv.w * fc0[96 + 2 * p + 1];
    l0 = fmaxf(l0, 0.f); l1 = fmaxf(l1, 0.f);
    *(float2*)(ans0 + (size_t)t * 96 + 2 * p) = make_float2(l0, l1);
    *(unsigned*)(Xh96 + (size_t)t * 96 + 2 * p) = pack2(l0, l1);
  }
}

// ---------------------------------------------------------------------------
// Phase B stages 2/3: lane-parallel payload preload, 8-wide Y gathers.
// (256,4): measured best — (256,8) thrashed L2/L3 (round 15).
// ---------------------------------------------------------------------------
template <int CIN, int RESID, int WBF16>
__global__ void __launch_bounds__(256, 4) b23(
    const float* __restrict__ xin, const float* __restrict__ fc,
    const int* __restrict__ ftstart, const unsigned* __restrict__ epk,
    const float4* __restrict__ ewt, const short* __restrict__ Y,
    const float* __restrict__ resid, float* __restrict__ dest,
    short* __restrict__ Xh64, int c0, int CC, int init, int fin) {
  int lane = threadIdx.x & 63;
  int t = __builtin_amdgcn_readfirstlane(blockIdx.x * 4 + (threadIdx.x >> 6));
  int q = lane >> 4;
  int sub = lane & 15;
  int cofs = (q & 1) + (q >> 1) * 8;
  int YW = CC * 64;
  float a0 = 0.f, a1 = 0.f, a2 = 0.f, a3 = 0.f;
  if (init) {
    const float* xr = xin + (size_t)t * CIN;
#pragma unroll
    for (int kk = 0; kk < CIN / 4; kk++) {
      int k = q * (CIN / 4) + kk;
      float xv = xr[k];
      float4 fv = *(const float4*)(fc + (size_t)k * 64 + 4 * sub);
      a0 = fmaf(xv, fv.x, a0);
      a1 = fmaf(xv, fv.y, a1);
      a2 = fmaf(xv, fv.z, a2);
      a3 = fmaf(xv, fv.w, a3);
    }
  }
  int s = __builtin_amdgcn_readfirstlane(ftstart[t]);
  int e1 = __builtin_amdgcn_readfirstlane(ftstart[t + 1]);
  for (int base = s; base < e1; base += 64) {
    int Ln = min(64, e1 - base);
    unsigned mypk = 0;
    float4 myw = make_float4(0.f, 0.f, 0.f, 0.f);
    if (lane < Ln) {
      mypk = epk[base + lane];
      myw = ewt[base + lane];
    }
    int j = 0;
    for (; j + 7 < Ln; j += 8) {
      float wq_[8];
      uint2 r_[8];
#pragma unroll
      for (int u = 0; u < 8; u++) {
        unsigned pk = __shfl(mypk, j + u, 64);
        float wx = __shfl(myw.x, j + u, 64), wy = __shfl(myw.y, j + u, 64);
        float wz = __shfl(myw.z, j + u, 64), ww = __shfl(myw.w, j + u, 64);
        wq_[u] = (q == 0) ? wx : (q == 1) ? wy : (q == 2) ? wz : ww;
        int src = pk & 16383;
        int cell = (int)(pk >> 14) + cofs - c0;
        r_[u] = make_uint2(0, 0);
        if ((unsigned)cell < (unsigned)CC)
          r_[u] = *(const uint2*)(Y + (size_t)src * YW + cell * 64 + 4 * sub);
      }
#pragma unroll
      for (int u = 0; u < 8; u++) {
        a0 = fmaf(wq_[u], b2f_lo(r_[u].x), a0);
        a1 = fmaf(wq_[u], b2f_hi(r_[u].x), a1);
        a2 = fmaf(wq_[u], b2f_lo(r_[u].y), a2);
        a3 = fmaf(wq_[u], b2f_hi(r_[u].y), a3);
      }
    }
    for (; j < Ln; j++) {
      unsigned pk = __shfl(mypk, j, 64);
      float wx = __shfl(myw.x, j, 64), wy = __shfl(myw.y, j, 64);
      float wz = __shfl(myw.z, j, 64), ww = __shfl(myw.w, j, 64);
      float wq = (q == 0) ? wx : (q == 1) ? wy : (q == 2) ? wz : ww;
      int src = pk & 16383;
      int cell = (int)(pk >> 14) + cofs - c0;
      if ((unsigned)cell < (unsigned)CC) {
        uint2 r = *(const uint2*)(Y + (size_t)src * YW + cell * 64 + 4 * sub);
        a0 = fmaf(wq, b2f_lo(r.x), a0);
        a1 = fmaf(wq, b2f_hi(r.x), a1);
        a2 = fmaf(wq, b2f_lo(r.y), a2);
        a3 = fmaf(wq, b2f_hi(r.y), a3);
      }
    }
  }
  a0 += __shfl_xor(a0, 16, 64); a1 += __shfl_xor(a1, 16, 64);
  a2 += __shfl_xor(a2, 16, 64); a3 += __shfl_xor(a3, 16, 64);
  a0 += __shfl_xor(a0, 32, 64); a1 += __shfl_xor(a1, 32, 64);
  a2 += __shfl_xor(a2, 32, 64); a3 += __shfl_xor(a3, 32, 64);
  if (lane < 16) {
    float4* dst = (float4*)(dest + (size_t)t * 64 + 4 * sub);
    if (!init) {
      float4 d = *dst;
      a0 += d.x; a1 += d.y; a2 += d.z; a3 += d.w;
    }
    if (RESID && init) {
      float4 rd = *(const float4*)(resid + (size_t)t * 64 + 4 * sub);
      a0 += rd.x; a1 += rd.y; a2 += rd.z; a3 += rd.w;
    }
    if (fin) {
      a0 = fmaxf(a0, 0.f); a1 = fmaxf(a1, 0.f);
      a2 = fmaxf(a2, 0.f); a3 = fmaxf(a3, 0.f);
    }
    *dst = make_float4(a0, a1, a2, a3);
    if (WBF16 && fin) {
      uint2 pkd = make_uint2(pack2(a0, a1), pack2(a2, a3));
      *(uint2*)(Xh64 + (size_t)t * 64 + 4 * sub) = pkd;
    }
  }
}

// ---------------------------------------------------------------------------
// Phase B stage 4: out[t] = gather(bf16 Y4h[NF][128]) + ans2@fc3. Single pass.
// ---------------------------------------------------------------------------
__global__ void __launch_bounds__(256, 8) b4_stage4(
    const float* __restrict__ ans2, const float* __restrict__ fc3,
    const int* __restrict__ ftstart, const unsigned* __restrict__ epk,
    const float4* __restrict__ ewt, const short* __restrict__ Y4h,
    float* __restrict__ outp) {
  int lane = threadIdx.x & 63;
  int t = blockIdx.x * 4 + (threadIdx.x >> 6);
  int s4 = ftstart[t] * 4, e4 = ftstart[t + 1] * 4;
  float m0 = 0.f, m1 = 0.f;
  for (int fq = s4 + lane; fq < e4; fq += 64) {
    int idx = fq >> 2, j = fq & 3;
    unsigned pk = epk[idx];
    float4 w4 = ewt[idx];
    int src = pk & 16383;
    int cell = (int)(pk >> 14) + (j & 1) + (j >> 1) * 8;
    float w = (j == 0) ? w4.x : (j == 1) ? w4.y : (j == 2) ? w4.z : w4.w;
    unsigned mm = *(const unsigned*)(Y4h + (size_t)src * 128 + cell * 2);
    m0 = fmaf(w, b2f_lo(mm), m0);
    m1 = fmaf(w, b2f_hi(mm), m1);
  }
  {
    float a = ans2[(size_t)t * 64 + lane];
    m0 += a * fc3[lane * 2 + 0];
    m1 += a * fc3[lane * 2 + 1];
  }
#pragma unroll
  for (int off = 32; off > 0; off >>= 1) {
    m0 += __shfl_xor(m0, off, 64);
    m1 += __shfl_xor(m1, off, 64);
  }
  if (lane == 0) {
    outp[t * 2] = m0;
    outp[t * 2 + 1] = m1;
  }
}

// ---------------------------------------------------------------------------
extern "C" void kernel_launch(void* const* d_in, const int* in_sizes, int n_in,
                              void* d_out, int out_size, void* d_ws, size_t ws_size,
                              hipStream_t stream) {
  const float* fp  = (const float*)d_in[0];
  const float* bp  = (const float*)d_in[1];
  const float* ff  = (const float*)d_in[2];
  const float* bfe = (const float*)d_in[3];
  const float* sup = (const float*)d_in[4];
  const int* fi  = (const int*)d_in[5];
  const int* fj  = (const int*)d_in[6];
  const int* bfi = (const int*)d_in[7];
  const int* bb  = (const int*)d_in[8];
  const float* W0 = (const float*)d_in[9];
  const float* W1 = (const float*)d_in[10];
  const float* W2 = (const float*)d_in[11];
  const float* W3 = (const float*)d_in[12];
  const float* W4 = (const float*)d_in[13];
  const float* fc0 = (const float*)d_in[14];
  const float* fc1 = (const float*)d_in[15];
  const float* fc2 = (const float*)d_in[16];
  const float* fc3 = (const float*)d_in[17];
  float* out = (float*)d_out;

  char* w = (char*)d_ws;
  size_t off = 0;
  auto alloc = [&](size_t bytes) {
    char* p = w + off;
    off += (bytes + 255) & ~size_t(255);
    return p;
  };
  float* ans0   = (float*)alloc((size_t)NF * 96 * 4);
  float* ans1   = (float*)alloc((size_t)NF * 64 * 4);
  float* ans2   = (float*)alloc((size_t)NF * 64 * 4);
  int* fthist  = (int*)alloc((size_t)NF * 4);
  int* bthist  = (int*)alloc((size_t)NF * 4);   // adjacent to fthist: one memset
  int* ftstart = (int*)alloc((size_t)(NF + 1) * 4);
  int* ftcur   = (int*)alloc((size_t)NF * 4);
  int* btstart = (int*)alloc((size_t)(NF + 1) * 4);
  int* btcur   = (int*)alloc((size_t)NF * 4);
  unsigned* fpk  = (unsigned*)alloc((size_t)EF * 4);
  float4* fwtP   = (float4*)alloc((size_t)EF * 16);
  unsigned* bpk  = (unsigned*)alloc((size_t)EB * 4);
  float4* bwtP   = (float4*)alloc((size_t)EB * 16);
  short* Xh96  = (short*)alloc((size_t)NF * 96 * 2);
  short* Xh64  = (short*)alloc((size_t)NF * 64 * 2);   // bf16 ans1
  short* Xh64b = (short*)alloc((size_t)NF * 64 * 2);   // bf16 ans2
  short* BT2 = (short*)alloc((size_t)4096 * 96 * 2);
  short* BT3 = (short*)alloc((size_t)4096 * 64 * 2);
  short* BT4 = (short*)alloc((size_t)128 * 64 * 2);
  float* W0T = (float*)alloc((size_t)8192 * 4);
  float* W1T = (float*)alloc((size_t)8192 * 4);
  char* Yreg = w + off;
  size_t avail = (ws_size > off) ? (ws_size - off) : 0;
  size_t percell = (size_t)NF * 64 * 2;
  int CC = 64;
  while (CC > 8 && (size_t)CC * percell > avail) CC >>= 1;
  int S = 64 / CC;
  short* Y   = (short*)Yreg;
  short* Y4h = (short*)Yreg;  // [NF][128] bf16, 4MB (reuses Y region)

  hipMemsetAsync(fthist, 0, (size_t)NF * 8, stream);

  build_weights<<<2624, 256, 0, stream>>>(W2, W3, W4, W0, W1, BT2, BT3, BT4, W0T, W1T);
  dual_hist<<<FBLK + BBLK, 256, 0, stream>>>(fi, bfi, fthist, bthist);
  csr_scan2<<<2, 1024, 0, stream>>>(fthist, bthist, ftstart, ftcur, btstart, btcur);
  dual_scatter_payload<<<FBLK + BBLK, 256, 0, stream>>>(fi, fj, bfi, bb, fp, bp, sup,
                                                        ftcur, btcur, fpk, fwtP, bpk, bwtP);

  // Stage 1: lane-parallel fused, 1 wave/node. Emits ans0 + bf16 Xh96.
  b1_stage1<<<NF / 4, 256, 0, stream>>>(ff, bfe, fc0, W0T, W1T,
                                        ftstart, fpk, fwtP, btstart, bpk, bwtP,
                                        ans0, Xh96);
  // Stage 2: MFMA GEMM + gather. Emits ans1 + bf16 Xh64.
  for (int c = 0; c < S; c++) {
    int c0 = c * CC;
    gemm_bf16<96><<<dim3(NF / 128, CC * 64 / 128), 256, 0, stream>>>(
        Xh96, BT2 + (size_t)c0 * 64 * 96, Y, CC * 64);
    b23<96, 0, 1><<<NF / 4, 256, 0, stream>>>(ans0, fc1, ftstart, fpk, fwtP,
                                              Y, nullptr, ans1, Xh64,
                                              c0, CC, c == 0, c == S - 1);
  }
  // Stage 3: emits ans2 + bf16 Xh64b.
  for (int c = 0; c < S; c++) {
    int c0 = c * CC;
    gemm_bf16<64><<<dim3(NF / 128, CC * 64 / 128), 256, 0, stream>>>(
        Xh64, BT3 + (size_t)c0 * 64 * 64, Y, CC * 64);
    b23<64, 1, 1><<<NF / 4, 256, 0, stream>>>(ans1, fc2, ftstart, fpk, fwtP,
                                              Y, ans1, ans2, Xh64b,
                                              c0, CC, c == 0, c == S - 1);
  }
  // Stage 4: W4 conv as a single MFMA GEMM [NF x 64] @ [64 x 128], then gather.
  gemm_bf16<64><<<dim3(NF / 128, 1), 256, 0, stream>>>(Xh64b, BT4, Y4h, 128);
  b4_stage4<<<NF / 4, 256, 0, stream>>>(ans2, fc3, ftstart, fpk, fwtP, Y4h, out);
}

// Round 18
// 294.348 us; speedup vs baseline: 1.3467x; 1.0658x over previous
//
#include <hip/hip_runtime.h>

#define NF 16384
#define NB 4096
#define EF 262144
#define EB 65536
#define FBLK 1024   // EF/256
#define BBLK 256    // EB/256

typedef __attribute__((ext_vector_type(8))) short bf16x8;
typedef __attribute__((ext_vector_type(4))) float f32x4;

__device__ __forceinline__ short f2b(float f) {
  unsigned u = __float_as_uint(f);
  u += 0x7fff + ((u >> 16) & 1);   // RNE
  return (short)(u >> 16);
}
__device__ __forceinline__ unsigned pack2(float lo, float hi) {
  return (unsigned)(unsigned short)f2b(lo) | ((unsigned)(unsigned short)f2b(hi) << 16);
}
__device__ __forceinline__ float b2f_lo(unsigned u) {
  return __uint_as_float(u << 16);
}
__device__ __forceinline__ float b2f_hi(unsigned u) {
  return __uint_as_float(u & 0xffff0000u);
}
__device__ __forceinline__ float b2fs(short s) {
  return __uint_as_float(((unsigned)(unsigned short)s) << 16);
}

// ---------------------------------------------------------------------------
// Target CSR: histogram (merged fluid+boundary).
// ---------------------------------------------------------------------------
__global__ void __launch_bounds__(256) dual_hist(const int* __restrict__ fi,
                                                 const int* __restrict__ bfi,
                                                 int* __restrict__ fhist,
                                                 int* __restrict__ bhist) {
  int bid = blockIdx.x;
  if (bid < FBLK) {
    int e = bid * 256 + threadIdx.x;
    atomicAdd(fhist + fi[e], 1);
  } else {
    int e = (bid - FBLK) * 256 + threadIdx.x;
    atomicAdd(bhist + bfi[e], 1);
  }
}

__global__ void __launch_bounds__(1024) csr_scan2(const int* __restrict__ fhist,
                                                  const int* __restrict__ bhist,
                                                  int* __restrict__ fstart, int* __restrict__ fcur,
                                                  int* __restrict__ bstart, int* __restrict__ bcur) {
  const int* hist = blockIdx.x ? bhist : fhist;
  int* start = blockIdx.x ? bstart : fstart;
  int* cursor = blockIdx.x ? bcur : fcur;
  __shared__ int wtot[16];
  int t = threadIdx.x;
  int lane = t & 63, wv = t >> 6;
  int base = t * 16;
  int vals[16];
  int s = 0;
#pragma unroll
  for (int k = 0; k < 16; k++) { vals[k] = hist[base + k]; s += vals[k]; }
  int ss = s;
  for (int off = 1; off < 64; off <<= 1) {
    int o = __shfl_up(ss, off, 64);
    if (lane >= off) ss += o;
  }
  if (lane == 63) wtot[wv] = ss;
  __syncthreads();
  if (t < 16) {
    int v = wtot[t];
    int vv = v;
    for (int off = 1; off < 16; off <<= 1) {
      int o = __shfl_up(vv, off, 64);
      if (t >= off) vv += o;
    }
    wtot[t] = vv - v;
  }
  __syncthreads();
  int run = ss - s + wtot[wv];
#pragma unroll
  for (int k = 0; k < 16; k++) { start[base + k] = run; cursor[base + k] = run; run += vals[k]; }
  if (t == 1023) start[16384] = run;
}

// ---------------------------------------------------------------------------
// Merged scatter + payload + tent-basis. Payload: pk (4B) + 4xbf16 wts (8B).
// ---------------------------------------------------------------------------
__global__ void __launch_bounds__(256) dual_scatter_payload(
    const int* __restrict__ fi, const int* __restrict__ fj,
    const int* __restrict__ bfi, const int* __restrict__ bb,
    const float* __restrict__ fp, const float* __restrict__ bp,
    const float* __restrict__ supportp,
    int* __restrict__ fcur, int* __restrict__ bcur,
    unsigned* __restrict__ fpk, uint2* __restrict__ fwh,
    unsigned* __restrict__ bpk, uint2* __restrict__ bwh) {
  int bid = blockIdx.x;
  bool fluid = bid < FBLK;
  int e = (fluid ? bid : bid - FBLK) * 256 + threadIdx.x;
  int ti = fluid ? fi[e] : bfi[e];
  int si = fluid ? fj[e] : bb[e];
  const float2* pT2 = (const float2*)fp;
  const float2* pS2 = fluid ? (const float2*)fp : (const float2*)bp;
  float sign = fluid ? -1.f : 1.f;
  float inv_sup = 1.0f / supportp[0];
  float2 pt = pT2[ti];
  float2 ps = pS2[si];
  // d = sign*(src-tgt)/support. (-1)*(+0) = -0 preserves reference signed
  // zeros for self-edges (atan2(-0,-0) = -pi).
  float dx = sign * ((ps.x - pt.x) * inv_sup);
  float dy = sign * ((ps.y - pt.y) * inv_sup);
  dx = fminf(fmaxf(dx, -1.f), 1.f);
  dy = fminf(fmaxf(dy, -1.f), 1.f);
  float r = sqrtf(dx * dx + dy * dy + 1e-12f);
  float theta;
  if (dx == 0.0f && dy == 0.0f) {
    float mag = __builtin_signbitf(dx) ? 3.14159265358979323846f : 0.0f;
    theta = __builtin_signbitf(dy) ? -mag : mag;
  } else {
    theta = atan2f(dy, dx);
  }
  float u = 2.f * r - 1.f;
  float v = theta * (1.f / 3.14159265358979323846f);
  float tu = (u + 1.f) * 3.5f;
  float tv = (v + 1.f) * 3.5f;
  int iu = min(max((int)floorf(tu), 0), 6);
  int iv = min(max((int)floorf(tv), 0), 6);
  float wu0 = fmaxf(0.f, 1.f - fabsf(tu - (float)iu));
  float wu1 = fmaxf(0.f, 1.f - fabsf(tu - (float)(iu + 1)));
  float wv0 = fmaxf(0.f, 1.f - fabsf(tv - (float)iv));
  float wv1 = fmaxf(0.f, 1.f - fabsf(tv - (float)(iv + 1)));
  unsigned pk = (unsigned)si | ((unsigned)(iu * 8 + iv) << 14);
  uint2 wh = make_uint2(pack2(wu0 * wv0, wu0 * wv1), pack2(wu1 * wv0, wu1 * wv1));
  if (fluid) {
    int p = atomicAdd(fcur + ti, 1);
    fpk[p] = pk; fwh[p] = wh;
  } else {
    int p = atomicAdd(bcur + ti, 1);
    bpk[p] = pk; bwh[p] = wh;
  }
}

// ---------------------------------------------------------------------------
// ALL weight prep in one launch: BT2 (4096x96), BT3 (4096x64), BT4 (128x64),
// W0T/W1T transposes.
// ---------------------------------------------------------------------------
__global__ void __launch_bounds__(256) build_weights(
    const float* __restrict__ W2, const float* __restrict__ W3,
    const float* __restrict__ W4, const float* __restrict__ W0,
    const float* __restrict__ W1,
    short* __restrict__ BT2, short* __restrict__ BT3, short* __restrict__ BT4,
    float* __restrict__ W0T, float* __restrict__ W1T) {
  int bid = blockIdx.x;
  if (bid < 1536) {                      // BT2: 393216 elems
    int tid = bid * 256 + threadIdx.x;
    int k = tid % 96, n = tid / 96;
    BT2[tid] = f2b(W2[((size_t)(n >> 6) * 96 + k) * 64 + (n & 63)]);
  } else if (bid < 2560) {               // BT3: 262144 elems
    int tid = (bid - 1536) * 256 + threadIdx.x;
    int k = tid & 63, n = tid >> 6;
    BT3[tid] = f2b(W3[((size_t)(n >> 6) * 64 + k) * 64 + (n & 63)]);
  } else if (bid < 2592) {               // BT4: 8192 elems
    int tid = (bid - 2560) * 256 + threadIdx.x;
    int k = tid & 63, n = tid >> 6;
    BT4[tid] = f2b(W4[((size_t)(n >> 1) * 64 + k) * 2 + (n & 1)]);
  } else {                               // W0T/W1T: 8192 elems each
    int tid = (bid - 2592) * 256 + threadIdx.x;
    int cell = tid >> 7, r = tid & 127;
    int p = r >> 3, k = (r >> 1) & 3, c = r & 1;
    int dst = cell * 128 + p * 8 + k * 2 + c;
    int src = cell * 128 + k * 32 + 2 * p + c;
    W0T[dst] = W0[src];
    W1T[dst] = W1[src];
  }
}

// ---------------------------------------------------------------------------
// Dense MFMA GEMM, LDS-staged tiles (conflict-free padded rows, 16B aligned).
// ---------------------------------------------------------------------------
template <int K>
__global__ void __launch_bounds__(256, 2) gemm_bf16(
    const short* __restrict__ A, const short* __restrict__ BT,
    short* __restrict__ C, int N) {
  constexpr int KP = K + 8;
  __shared__ __align__(16) short Al[128 * KP];
  __shared__ __align__(16) short Bl[128 * KP];
  int tid = threadIdx.x;
  int lane = tid & 63;
  int w = tid >> 6;
  int m0b = blockIdx.x * 128;
  int n0b = blockIdx.y * 128;
  constexpr int ROWV = K / 8;
  for (int f = tid; f < 128 * ROWV; f += 256) {
    int r = f / ROWV, c = f % ROWV;
    *(float4*)(Al + r * KP + c * 8) = *(const float4*)(A + (size_t)(m0b + r) * K + c * 8);
    *(float4*)(Bl + r * KP + c * 8) = *(const float4*)(BT + (size_t)(n0b + r) * K + c * 8);
  }
  __syncthreads();
  int m0 = (w & 1) * 64;
  int n0 = (w >> 1) * 64;
  int fr = lane & 15;
  int kg = lane >> 4;
  f32x4 acc[4][4] = {};
#pragma unroll
  for (int kc = 0; kc < K; kc += 32) {
    bf16x8 a[4], b[4];
#pragma unroll
    for (int i = 0; i < 4; i++) {
      a[i] = *(const bf16x8*)(Al + (m0 + i * 16 + fr) * KP + kc + kg * 8);
      b[i] = *(const bf16x8*)(Bl + (n0 + i * 16 + fr) * KP + kc + kg * 8);
    }
#pragma unroll
    for (int i = 0; i < 4; i++)
#pragma unroll
      for (int j = 0; j < 4; j++)
        acc[i][j] = __builtin_amdgcn_mfma_f32_16x16x32_bf16(a[i], b[j], acc[i][j], 0, 0, 0);
  }
#pragma unroll
  for (int i = 0; i < 4; i++) {
    int row = m0b + m0 + i * 16 + (lane >> 4) * 4;
#pragma unroll
    for (int j = 0; j < 4; j++) {
      int col = n0b + n0 + j * 16 + (lane & 15);
#pragma unroll
      for (int r = 0; r < 4; r++)
        C[(size_t)(row + r) * N + col] = f2b(acc[i][j][r]);
    }
  }
}

// ---------------------------------------------------------------------------
// Stage 1, lane-parallel payload + 4-edge unrolled broadcast loop (W0T/W1T).
// Writes ONLY bf16 Xh96 (fp32 ans0 eliminated — its sole consumer reads bf16).
// ---------------------------------------------------------------------------
__global__ void __launch_bounds__(256, 8) b1_stage1(
    const float* __restrict__ ff, const float* __restrict__ bfe,
    const float* __restrict__ fc0,
    const float* __restrict__ W0T, const float* __restrict__ W1T,
    const int* __restrict__ ftstart, const unsigned* __restrict__ fpk,
    const uint2* __restrict__ fwh,
    const int* __restrict__ btstart, const unsigned* __restrict__ bpk,
    const uint2* __restrict__ bwh,
    short* __restrict__ Xh96) {
  int lane = threadIdx.x & 63;
  int t = __builtin_amdgcn_readfirstlane(blockIdx.x * 4 + (threadIdx.x >> 6));
  int q = lane >> 4;
  int p = lane & 15;

  auto run_side = [&](const int* st, const unsigned* pkA, const uint2* whA,
                      const float* xA, const float* WT) -> float2 {
    float2 acc = make_float2(0.f, 0.f);
    int s = __builtin_amdgcn_readfirstlane(st[t]);
    int e1 = __builtin_amdgcn_readfirstlane(st[t + 1]);
    int cofs = (q & 1) + (q >> 1) * 8;
    for (int base = s; base < e1; base += 64) {
      int Ln = min(64, e1 - base);
      unsigned mypk = 0;
      uint2 mywh = make_uint2(0u, 0u);
      float4 myx = make_float4(0.f, 0.f, 0.f, 0.f);
      if (lane < Ln) {
        mypk = pkA[base + lane];
        mywh = whA[base + lane];
        myx = *(const float4*)(xA + (size_t)(mypk & 16383) * 4);
      }
      int j = 0;
      for (; j + 3 < Ln; j += 4) {
        unsigned pk_[4];
        float wq_[4], xx_[4], xy_[4], xz_[4], xw_[4];
#pragma unroll
        for (int u = 0; u < 4; u++) {
          pk_[u] = __shfl(mypk, j + u, 64);
          unsigned wlo = __shfl(mywh.x, j + u, 64);
          unsigned whi = __shfl(mywh.y, j + u, 64);
          unsigned wsel = (q < 2) ? wlo : whi;
          wq_[u] = (q & 1) ? b2f_hi(wsel) : b2f_lo(wsel);
          xx_[u] = __shfl(myx.x, j + u, 64);
          xy_[u] = __shfl(myx.y, j + u, 64);
          xz_[u] = __shfl(myx.z, j + u, 64);
          xw_[u] = __shfl(myx.w, j + u, 64);
        }
        float4 A_[4], B_[4];
#pragma unroll
        for (int u = 0; u < 4; u++) {
          int cell = (int)(pk_[u] >> 14) + cofs;
          const float4* Wt = (const float4*)(WT + cell * 128 + p * 8);
          A_[u] = Wt[0];
          B_[u] = Wt[1];
        }
#pragma unroll
        for (int u = 0; u < 4; u++) {
          acc.x = fmaf(wq_[u],
                       xx_[u] * A_[u].x + xy_[u] * A_[u].z + xz_[u] * B_[u].x + xw_[u] * B_[u].z,
                       acc.x);
          acc.y = fmaf(wq_[u],
                       xx_[u] * A_[u].y + xy_[u] * A_[u].w + xz_[u] * B_[u].y + xw_[u] * B_[u].w,
                       acc.y);
        }
      }
      for (; j < Ln; j++) {
        unsigned pk = __shfl(mypk, j, 64);
        unsigned wlo = __shfl(mywh.x, j, 64);
        unsigned whi = __shfl(mywh.y, j, 64);
        unsigned wsel = (q < 2) ? wlo : whi;
        float wq = (q & 1) ? b2f_hi(wsel) : b2f_lo(wsel);
        float xx = __shfl(myx.x, j, 64), xy = __shfl(myx.y, j, 64);
        float xz = __shfl(myx.z, j, 64), xw = __shfl(myx.w, j, 64);
        int cell = (int)(pk >> 14) + cofs;
        const float4* Wt = (const float4*)(WT + cell * 128 + p * 8);
        float4 A = Wt[0], B = Wt[1];
        acc.x = fmaf(wq, xx * A.x + xy * A.z + xz * B.x + xw * B.z, acc.x);
        acc.y = fmaf(wq, xx * A.y + xy * A.w + xz * B.y + xw * B.w, acc.y);
      }
    }
    return acc;
  };

  float2 fa = run_side(ftstart, fpk, fwh, ff, W0T);
  float2 ba = run_side(btstart, bpk, bwh, bfe, W1T);

  fa.x += __shfl_xor(fa.x, 16, 64); fa.y += __shfl_xor(fa.y, 16, 64);
  fa.x += __shfl_xor(fa.x, 32, 64); fa.y += __shfl_xor(fa.y, 32, 64);
  ba.x += __shfl_xor(ba.x, 16, 64); ba.y += __shfl_xor(ba.y, 16, 64);
  ba.x += __shfl_xor(ba.x, 32, 64); ba.y += __shfl_xor(ba.y, 32, 64);
  if (lane < 16) {
    fa.x = fmaxf(fa.x, 0.f); fa.y = fmaxf(fa.y, 0.f);
    *(unsigned*)(Xh96 + (size_t)t * 96 + 32 + 2 * p) = pack2(fa.x, fa.y);
  } else if (lane < 32) {
    ba.x = fmaxf(ba.x, 0.f); ba.y = fmaxf(ba.y, 0.f);
    *(unsigned*)(Xh96 + (size_t)t * 96 + 64 + 2 * p) = pack2(ba.x, ba.y);
  } else if (lane < 48) {
    float4 fv = *(const float4*)(ff + (size_t)t * 4);
    float l0 = fv.x * fc0[2 * p] + fv.y * fc0[32 + 2 * p] +
               fv.z * fc0[64 + 2 * p] + fv.w * fc0[96 + 2 * p];
    float l1 = fv.x * fc0[2 * p + 1] + fv.y * fc0[32 + 2 * p + 1] +
               fv.z * fc0[64 + 2 * p + 1] + fv.w * fc0[96 + 2 * p + 1];
    l0 = fmaxf(l0, 0.f); l1 = fmaxf(l1, 0.f);
    *(unsigned*)(Xh96 + (size_t)t * 96 + 2 * p) = pack2(l0, l1);
  }
}

// ---------------------------------------------------------------------------
// Phase B stages 2/3: lane-parallel payload preload, 8-wide Y gathers.
// xin/resid are bf16 (Xh*); carry buffer (dest, fp32) written only when !fin;
// at fin only the bf16 product Xh64 is written. (256,4) — measured best.
// ---------------------------------------------------------------------------
template <int CIN, int RESID>
__global__ void __launch_bounds__(256, 4) b23(
    const short* __restrict__ xin, const float* __restrict__ fc,
    const int* __restrict__ ftstart, const unsigned* __restrict__ epk,
    const uint2* __restrict__ ewh, const short* __restrict__ Y,
    const short* __restrict__ resid, float* __restrict__ dest,
    short* __restrict__ Xh64, int c0, int CC, int init, int fin) {
  int lane = threadIdx.x & 63;
  int t = __builtin_amdgcn_readfirstlane(blockIdx.x * 4 + (threadIdx.x >> 6));
  int q = lane >> 4;
  int sub = lane & 15;
  int cofs = (q & 1) + (q >> 1) * 8;
  int YW = CC * 64;
  float a0 = 0.f, a1 = 0.f, a2 = 0.f, a3 = 0.f;
  if (init) {
    constexpr int KQ = CIN / 4;  // k's per quarter
    const unsigned* xr32 = (const unsigned*)(xin + (size_t)t * CIN) + q * (KQ / 2);
#pragma unroll
    for (int kk = 0; kk < KQ / 2; kk++) {
      unsigned uu = xr32[kk];
      int k = q * KQ + 2 * kk;
      float xlo = b2f_lo(uu), xhi = b2f_hi(uu);
      float4 f0 = *(const float4*)(fc + (size_t)k * 64 + 4 * sub);
      float4 f1 = *(const float4*)(fc + (size_t)(k + 1) * 64 + 4 * sub);
      a0 = fmaf(xlo, f0.x, a0); a1 = fmaf(xlo, f0.y, a1);
      a2 = fmaf(xlo, f0.z, a2); a3 = fmaf(xlo, f0.w, a3);
      a0 = fmaf(xhi, f1.x, a0); a1 = fmaf(xhi, f1.y, a1);
      a2 = fmaf(xhi, f1.z, a2); a3 = fmaf(xhi, f1.w, a3);
    }
  }
  int s = __builtin_amdgcn_readfirstlane(ftstart[t]);
  int e1 = __builtin_amdgcn_readfirstlane(ftstart[t + 1]);
  for (int base = s; base < e1; base += 64) {
    int Ln = min(64, e1 - base);
    unsigned mypk = 0;
    uint2 mywh = make_uint2(0u, 0u);
    if (lane < Ln) {
      mypk = epk[base + lane];
      mywh = ewh[base + lane];
    }
    int j = 0;
    for (; j + 7 < Ln; j += 8) {
      float wq_[8];
      uint2 r_[8];
#pragma unroll
      for (int u = 0; u < 8; u++) {
        unsigned pk = __shfl(mypk, j + u, 64);
        unsigned wlo = __shfl(mywh.x, j + u, 64);
        unsigned whi = __shfl(mywh.y, j + u, 64);
        unsigned wsel = (q < 2) ? wlo : whi;
        wq_[u] = (q & 1) ? b2f_hi(wsel) : b2f_lo(wsel);
        int src = pk & 16383;
        int cell = (int)(pk >> 14) + cofs - c0;
        r_[u] = make_uint2(0, 0);
        if ((unsigned)cell < (unsigned)CC)
          r_[u] = *(const uint2*)(Y + (size_t)src * YW + cell * 64 + 4 * sub);
      }
#pragma unroll
      for (int u = 0; u < 8; u++) {
        a0 = fmaf(wq_[u], b2f_lo(r_[u].x), a0);
        a1 = fmaf(wq_[u], b2f_hi(r_[u].x), a1);
        a2 = fmaf(wq_[u], b2f_lo(r_[u].y), a2);
        a3 = fmaf(wq_[u], b2f_hi(r_[u].y), a3);
      }
    }
    for (; j < Ln; j++) {
      unsigned pk = __shfl(mypk, j, 64);
      unsigned wlo = __shfl(mywh.x, j, 64);
      unsigned whi = __shfl(mywh.y, j, 64);
      unsigned wsel = (q < 2) ? wlo : whi;
      float wq = (q & 1) ? b2f_hi(wsel) : b2f_lo(wsel);
      int src = pk & 16383;
      int cell = (int)(pk >> 14) + cofs - c0;
      if ((unsigned)cell < (unsigned)CC) {
        uint2 r = *(const uint2*)(Y + (size_t)src * YW + cell * 64 + 4 * sub);
        a0 = fmaf(wq, b2f_lo(r.x), a0);
        a1 = fmaf(wq, b2f_hi(r.x), a1);
        a2 = fmaf(wq, b2f_lo(r.y), a2);
        a3 = fmaf(wq, b2f_hi(r.y), a3);
      }
    }
  }
  a0 += __shfl_xor(a0, 16, 64); a1 += __shfl_xor(a1, 16, 64);
  a2 += __shfl_xor(a2, 16, 64); a3 += __shfl_xor(a3, 16, 64);
  a0 += __shfl_xor(a0, 32, 64); a1 += __shfl_xor(a1, 32, 64);
  a2 += __shfl_xor(a2, 32, 64); a3 += __shfl_xor(a3, 32, 64);
  if (lane < 16) {
    float4* dst = (float4*)(dest + (size_t)t * 64 + 4 * sub);
    if (!init) {
      float4 d = *dst;
      a0 += d.x; a1 += d.y; a2 += d.z; a3 += d.w;
    }
    if (RESID && init) {
      uint2 rr = *(const uint2*)(resid + (size_t)t * 64 + 4 * sub);
      a0 += b2f_lo(rr.x); a1 += b2f_hi(rr.x);
      a2 += b2f_lo(rr.y); a3 += b2f_hi(rr.y);
    }
    if (fin) {
      a0 = fmaxf(a0, 0.f); a1 = fmaxf(a1, 0.f);
      a2 = fmaxf(a2, 0.f); a3 = fmaxf(a3, 0.f);
      uint2 pkd = make_uint2(pack2(a0, a1), pack2(a2, a3));
      *(uint2*)(Xh64 + (size_t)t * 64 + 4 * sub) = pkd;
    } else {
      *dst = make_float4(a0, a1, a2, a3);
    }
  }
}

// ---------------------------------------------------------------------------
// Phase B stage 4: out[t] = gather(bf16 Y4h[NF][128]) + bf16(ans2)@fc3.
// ---------------------------------------------------------------------------
__global__ void __launch_bounds__(256, 8) b4_stage4(
    const short* __restrict__ Xh64b, const float* __restrict__ fc3,
    const int* __restrict__ ftstart, const unsigned* __restrict__ epk,
    const uint2* __restrict__ ewh, const short* __restrict__ Y4h,
    float* __restrict__ outp) {
  int lane = threadIdx.x & 63;
  int t = blockIdx.x * 4 + (threadIdx.x >> 6);
  int s4 = ftstart[t] * 4, e4 = ftstart[t + 1] * 4;
  float m0 = 0.f, m1 = 0.f;
  for (int fq = s4 + lane; fq < e4; fq += 64) {
    int idx = fq >> 2, j = fq & 3;
    unsigned pk = epk[idx];
    uint2 wh = ewh[idx];
    int src = pk & 16383;
    int cell = (int)(pk >> 14) + (j & 1) + (j >> 1) * 8;
    unsigned wsel = (j < 2) ? wh.x : wh.y;
    float w = (j & 1) ? b2f_hi(wsel) : b2f_lo(wsel);
    unsigned mm = *(const unsigned*)(Y4h + (size_t)src * 128 + cell * 2);
    m0 = fmaf(w, b2f_lo(mm), m0);
    m1 = fmaf(w, b2f_hi(mm), m1);
  }
  {
    float a = b2fs(Xh64b[(size_t)t * 64 + lane]);
    m0 += a * fc3[lane * 2 + 0];
    m1 += a * fc3[lane * 2 + 1];
  }
#pragma unroll
  for (int off = 32; off > 0; off >>= 1) {
    m0 += __shfl_xor(m0, off, 64);
    m1 += __shfl_xor(m1, off, 64);
  }
  if (lane == 0) {
    outp[t * 2] = m0;
    outp[t * 2 + 1] = m1;
  }
}

// ---------------------------------------------------------------------------
extern "C" void kernel_launch(void* const* d_in, const int* in_sizes, int n_in,
                              void* d_out, int out_size, void* d_ws, size_t ws_size,
                              hipStream_t stream) {
  const float* fp  = (const float*)d_in[0];
  const float* bp  = (const float*)d_in[1];
  const float* ff  = (const float*)d_in[2];
  const float* bfe = (const float*)d_in[3];
  const float* sup = (const float*)d_in[4];
  const int* fi  = (const int*)d_in[5];
  const int* fj  = (const int*)d_in[6];
  const int* bfi = (const int*)d_in[7];
  const int* bb  = (const int*)d_in[8];
  const float* W0 = (const float*)d_in[9];
  const float* W1 = (const float*)d_in[10];
  const float* W2 = (const float*)d_in[11];
  const float* W3 = (const float*)d_in[12];
  const float* W4 = (const float*)d_in[13];
  const float* fc0 = (const float*)d_in[14];
  const float* fc1 = (const float*)d_in[15];
  const float* fc2 = (const float*)d_in[16];
  const float* fc3 = (const float*)d_in[17];
  float* out = (float*)d_out;

  char* w = (char*)d_ws;
  size_t off = 0;
  auto alloc = [&](size_t bytes) {
    char* p = w + off;
    off += (bytes + 255) & ~size_t(255);
    return p;
  };
  float* ans1   = (float*)alloc((size_t)NF * 64 * 4);   // inter-pass carry only
  float* ans2   = (float*)alloc((size_t)NF * 64 * 4);   // inter-pass carry only
  int* fthist  = (int*)alloc((size_t)NF * 4);
  int* bthist  = (int*)alloc((size_t)NF * 4);   // adjacent to fthist: one memset
  int* ftstart = (int*)alloc((size_t)(NF + 1) * 4);
  int* ftcur   = (int*)alloc((size_t)NF * 4);
  int* btstart = (int*)alloc((size_t)(NF + 1) * 4);
  int* btcur   = (int*)alloc((size_t)NF * 4);
  unsigned* fpk  = (unsigned*)alloc((size_t)EF * 4);
  uint2* fwh     = (uint2*)alloc((size_t)EF * 8);
  unsigned* bpk  = (unsigned*)alloc((size_t)EB * 4);
  uint2* bwh     = (uint2*)alloc((size_t)EB * 8);
  short* Xh96  = (short*)alloc((size_t)NF * 96 * 2);
  short* Xh64  = (short*)alloc((size_t)NF * 64 * 2);   // bf16 ans1
  short* Xh64b = (short*)alloc((size_t)NF * 64 * 2);   // bf16 ans2
  short* BT2 = (short*)alloc((size_t)4096 * 96 * 2);
  short* BT3 = (short*)alloc((size_t)4096 * 64 * 2);
  short* BT4 = (short*)alloc((size_t)128 * 64 * 2);
  float* W0T = (float*)alloc((size_t)8192 * 4);
  float* W1T = (float*)alloc((size_t)8192 * 4);
  char* Yreg = w + off;
  size_t avail = (ws_size > off) ? (ws_size - off) : 0;
  size_t percell = (size_t)NF * 64 * 2;
  int CC = 64;
  while (CC > 8 && (size_t)CC * percell > avail) CC >>= 1;
  int S = 64 / CC;
  short* Y   = (short*)Yreg;
  short* Y4h = (short*)Yreg;  // [NF][128] bf16, 4MB (reuses Y region)

  hipMemsetAsync(fthist, 0, (size_t)NF * 8, stream);

  build_weights<<<2624, 256, 0, stream>>>(W2, W3, W4, W0, W1, BT2, BT3, BT4, W0T, W1T);
  dual_hist<<<FBLK + BBLK, 256, 0, stream>>>(fi, bfi, fthist, bthist);
  csr_scan2<<<2, 1024, 0, stream>>>(fthist, bthist, ftstart, ftcur, btstart, btcur);
  dual_scatter_payload<<<FBLK + BBLK, 256, 0, stream>>>(fi, fj, bfi, bb, fp, bp, sup,
                                                        ftcur, btcur, fpk, fwh, bpk, bwh);

  // Stage 1: lane-parallel fused, 1 wave/node. Emits bf16 Xh96 only.
  b1_stage1<<<NF / 4, 256, 0, stream>>>(ff, bfe, fc0, W0T, W1T,
                                        ftstart, fpk, fwh, btstart, bpk, bwh, Xh96);
  // Stage 2: MFMA GEMM + gather. Emits bf16 Xh64 (fp32 ans1 = carry only).
  for (int c = 0; c < S; c++) {
    int c0 = c * CC;
    gemm_bf16<96><<<dim3(NF / 128, CC * 64 / 128), 256, 0, stream>>>(
        Xh96, BT2 + (size_t)c0 * 64 * 96, Y, CC * 64);
    b23<96, 0><<<NF / 4, 256, 0, stream>>>(Xh96, fc1, ftstart, fpk, fwh,
                                           Y, nullptr, ans1, Xh64,
                                           c0, CC, c == 0, c == S - 1);
  }
  // Stage 3: emits bf16 Xh64b (fp32 ans2 = carry only).
  for (int c = 0; c < S; c++) {
    int c0 = c * CC;
    gemm_bf16<64><<<dim3(NF / 128, CC * 64 / 128), 256, 0, stream>>>(
        Xh64, BT3 + (size_t)c0 * 64 * 64, Y, CC * 64);
    b23<64, 1><<<NF / 4, 256, 0, stream>>>(Xh64, fc2, ftstart, fpk, fwh,
                                           Y, Xh64, ans2, Xh64b,
                                           c0, CC, c == 0, c == S - 1);
  }
  // Stage 4: W4 conv as a single MFMA GEMM [NF x 64] @ [64 x 128], then gather.
  gemm_bf16<64><<<dim3(NF / 128, 1), 256, 0, stream>>>(Xh64b, BT4, Y4h, 128);
  b4_stage4<<<NF / 4, 256, 0, stream>>>(Xh64b, fc3, ftstart, fpk, fwh, Y4h, out);
}

// Round 19
// 292.651 us; speedup vs baseline: 1.3545x; 1.0058x over previous
//
#include <hip/hip_runtime.h>

#define NF 16384
#define NB 4096
#define EF 262144
#define EB 65536
#define FBLK 1024   // EF/256
#define BBLK 256    // EB/256

typedef __attribute__((ext_vector_type(8))) short bf16x8;
typedef __attribute__((ext_vector_type(4))) float f32x4;

__device__ __forceinline__ short f2b(float f) {
  unsigned u = __float_as_uint(f);
  u += 0x7fff + ((u >> 16) & 1);   // RNE
  return (short)(u >> 16);
}
__device__ __forceinline__ unsigned pack2(float lo, float hi) {
  return (unsigned)(unsigned short)f2b(lo) | ((unsigned)(unsigned short)f2b(hi) << 16);
}
__device__ __forceinline__ float b2f_lo(unsigned u) {
  return __uint_as_float(u << 16);
}
__device__ __forceinline__ float b2f_hi(unsigned u) {
  return __uint_as_float(u & 0xffff0000u);
}
__device__ __forceinline__ float b2fs(short s) {
  return __uint_as_float(((unsigned)(unsigned short)s) << 16);
}

// ---------------------------------------------------------------------------
// Target CSR: histogram (merged fluid+boundary).
// ---------------------------------------------------------------------------
__global__ void __launch_bounds__(256) dual_hist(const int* __restrict__ fi,
                                                 const int* __restrict__ bfi,
                                                 int* __restrict__ fhist,
                                                 int* __restrict__ bhist) {
  int bid = blockIdx.x;
  if (bid < FBLK) {
    int e = bid * 256 + threadIdx.x;
    atomicAdd(fhist + fi[e], 1);
  } else {
    int e = (bid - FBLK) * 256 + threadIdx.x;
    atomicAdd(bhist + bfi[e], 1);
  }
}

__global__ void __launch_bounds__(1024) csr_scan2(const int* __restrict__ fhist,
                                                  const int* __restrict__ bhist,
                                                  int* __restrict__ fstart, int* __restrict__ fcur,
                                                  int* __restrict__ bstart, int* __restrict__ bcur) {
  const int* hist = blockIdx.x ? bhist : fhist;
  int* start = blockIdx.x ? bstart : fstart;
  int* cursor = blockIdx.x ? bcur : fcur;
  __shared__ int wtot[16];
  int t = threadIdx.x;
  int lane = t & 63, wv = t >> 6;
  int base = t * 16;
  int vals[16];
  int s = 0;
#pragma unroll
  for (int k = 0; k < 16; k++) { vals[k] = hist[base + k]; s += vals[k]; }
  int ss = s;
  for (int off = 1; off < 64; off <<= 1) {
    int o = __shfl_up(ss, off, 64);
    if (lane >= off) ss += o;
  }
  if (lane == 63) wtot[wv] = ss;
  __syncthreads();
  if (t < 16) {
    int v = wtot[t];
    int vv = v;
    for (int off = 1; off < 16; off <<= 1) {
      int o = __shfl_up(vv, off, 64);
      if (t >= off) vv += o;
    }
    wtot[t] = vv - v;
  }
  __syncthreads();
  int run = ss - s + wtot[wv];
#pragma unroll
  for (int k = 0; k < 16; k++) { start[base + k] = run; cursor[base + k] = run; run += vals[k]; }
  if (t == 1023) start[16384] = run;
}

// ---------------------------------------------------------------------------
// Merged scatter + payload + tent-basis. Payload: pk (4B) + 4xbf16 wts (8B).
// ---------------------------------------------------------------------------
__global__ void __launch_bounds__(256) dual_scatter_payload(
    const int* __restrict__ fi, const int* __restrict__ fj,
    const int* __restrict__ bfi, const int* __restrict__ bb,
    const float* __restrict__ fp, const float* __restrict__ bp,
    const float* __restrict__ supportp,
    int* __restrict__ fcur, int* __restrict__ bcur,
    unsigned* __restrict__ fpk, uint2* __restrict__ fwh,
    unsigned* __restrict__ bpk, uint2* __restrict__ bwh) {
  int bid = blockIdx.x;
  bool fluid = bid < FBLK;
  int e = (fluid ? bid : bid - FBLK) * 256 + threadIdx.x;
  int ti = fluid ? fi[e] : bfi[e];
  int si = fluid ? fj[e] : bb[e];
  const float2* pT2 = (const float2*)fp;
  const float2* pS2 = fluid ? (const float2*)fp : (const float2*)bp;
  float sign = fluid ? -1.f : 1.f;
  float inv_sup = 1.0f / supportp[0];
  float2 pt = pT2[ti];
  float2 ps = pS2[si];
  // d = sign*(src-tgt)/support. (-1)*(+0) = -0 preserves reference signed
  // zeros for self-edges (atan2(-0,-0) = -pi).
  float dx = sign * ((ps.x - pt.x) * inv_sup);
  float dy = sign * ((ps.y - pt.y) * inv_sup);
  dx = fminf(fmaxf(dx, -1.f), 1.f);
  dy = fminf(fmaxf(dy, -1.f), 1.f);
  float r = sqrtf(dx * dx + dy * dy + 1e-12f);
  float theta;
  if (dx == 0.0f && dy == 0.0f) {
    float mag = __builtin_signbitf(dx) ? 3.14159265358979323846f : 0.0f;
    theta = __builtin_signbitf(dy) ? -mag : mag;
  } else {
    theta = atan2f(dy, dx);
  }
  float u = 2.f * r - 1.f;
  float v = theta * (1.f / 3.14159265358979323846f);
  float tu = (u + 1.f) * 3.5f;
  float tv = (v + 1.f) * 3.5f;
  int iu = min(max((int)floorf(tu), 0), 6);
  int iv = min(max((int)floorf(tv), 0), 6);
  float wu0 = fmaxf(0.f, 1.f - fabsf(tu - (float)iu));
  float wu1 = fmaxf(0.f, 1.f - fabsf(tu - (float)(iu + 1)));
  float wv0 = fmaxf(0.f, 1.f - fabsf(tv - (float)iv));
  float wv1 = fmaxf(0.f, 1.f - fabsf(tv - (float)(iv + 1)));
  unsigned pk = (unsigned)si | ((unsigned)(iu * 8 + iv) << 14);
  uint2 wh = make_uint2(pack2(wu0 * wv0, wu0 * wv1), pack2(wu1 * wv0, wu1 * wv1));
  if (fluid) {
    int p = atomicAdd(fcur + ti, 1);
    fpk[p] = pk; fwh[p] = wh;
  } else {
    int p = atomicAdd(bcur + ti, 1);
    bpk[p] = pk; bwh[p] = wh;
  }
}

// ---------------------------------------------------------------------------
// ALL weight prep in one launch: BT2 (4096x96), BT3 (4096x64), BT4 (128x64),
// W0T/W1T transposes.
// ---------------------------------------------------------------------------
__global__ void __launch_bounds__(256) build_weights(
    const float* __restrict__ W2, const float* __restrict__ W3,
    const float* __restrict__ W4, const float* __restrict__ W0,
    const float* __restrict__ W1,
    short* __restrict__ BT2, short* __restrict__ BT3, short* __restrict__ BT4,
    float* __restrict__ W0T, float* __restrict__ W1T) {
  int bid = blockIdx.x;
  if (bid < 1536) {                      // BT2: 393216 elems
    int tid = bid * 256 + threadIdx.x;
    int k = tid % 96, n = tid / 96;
    BT2[tid] = f2b(W2[((size_t)(n >> 6) * 96 + k) * 64 + (n & 63)]);
  } else if (bid < 2560) {               // BT3: 262144 elems
    int tid = (bid - 1536) * 256 + threadIdx.x;
    int k = tid & 63, n = tid >> 6;
    BT3[tid] = f2b(W3[((size_t)(n >> 6) * 64 + k) * 64 + (n & 63)]);
  } else if (bid < 2592) {               // BT4: 8192 elems
    int tid = (bid - 2560) * 256 + threadIdx.x;
    int k = tid & 63, n = tid >> 6;
    BT4[tid] = f2b(W4[((size_t)(n >> 1) * 64 + k) * 2 + (n & 1)]);
  } else {                               // W0T/W1T: 8192 elems each
    int tid = (bid - 2592) * 256 + threadIdx.x;
    int cell = tid >> 7, r = tid & 127;
    int p = r >> 3, k = (r >> 1) & 3, c = r & 1;
    int dst = cell * 128 + p * 8 + k * 2 + c;
    int src = cell * 128 + k * 32 + 2 * p + c;
    W0T[dst] = W0[src];
    W1T[dst] = W1[src];
  }
}

// ---------------------------------------------------------------------------
// Dense MFMA GEMM, LDS-staged tiles (conflict-free padded rows, 16B aligned).
// ---------------------------------------------------------------------------
template <int K>
__global__ void __launch_bounds__(256, 2) gemm_bf16(
    const short* __restrict__ A, const short* __restrict__ BT,
    short* __restrict__ C, int N) {
  constexpr int KP = K + 8;
  __shared__ __align__(16) short Al[128 * KP];
  __shared__ __align__(16) short Bl[128 * KP];
  int tid = threadIdx.x;
  int lane = tid & 63;
  int w = tid >> 6;
  int m0b = blockIdx.x * 128;
  int n0b = blockIdx.y * 128;
  constexpr int ROWV = K / 8;
  for (int f = tid; f < 128 * ROWV; f += 256) {
    int r = f / ROWV, c = f % ROWV;
    *(float4*)(Al + r * KP + c * 8) = *(const float4*)(A + (size_t)(m0b + r) * K + c * 8);
    *(float4*)(Bl + r * KP + c * 8) = *(const float4*)(BT + (size_t)(n0b + r) * K + c * 8);
  }
  __syncthreads();
  int m0 = (w & 1) * 64;
  int n0 = (w >> 1) * 64;
  int fr = lane & 15;
  int kg = lane >> 4;
  f32x4 acc[4][4] = {};
#pragma unroll
  for (int kc = 0; kc < K; kc += 32) {
    bf16x8 a[4], b[4];
#pragma unroll
    for (int i = 0; i < 4; i++) {
      a[i] = *(const bf16x8*)(Al + (m0 + i * 16 + fr) * KP + kc + kg * 8);
      b[i] = *(const bf16x8*)(Bl + (n0 + i * 16 + fr) * KP + kc + kg * 8);
    }
#pragma unroll
    for (int i = 0; i < 4; i++)
#pragma unroll
      for (int j = 0; j < 4; j++)
        acc[i][j] = __builtin_amdgcn_mfma_f32_16x16x32_bf16(a[i], b[j], acc[i][j], 0, 0, 0);
  }
#pragma unroll
  for (int i = 0; i < 4; i++) {
    int row = m0b + m0 + i * 16 + (lane >> 4) * 4;
#pragma unroll
    for (int j = 0; j < 4; j++) {
      int col = n0b + n0 + j * 16 + (lane & 15);
#pragma unroll
      for (int r = 0; r < 4; r++)
        C[(size_t)(row + r) * N + col] = f2b(acc[i][j][r]);
    }
  }
}

// ---------------------------------------------------------------------------
// Stage 1, lane-parallel payload + 4-edge unrolled broadcast loop (W0T/W1T).
// Writes ONLY bf16 Xh96.
// ---------------------------------------------------------------------------
__global__ void __launch_bounds__(256, 8) b1_stage1(
    const float* __restrict__ ff, const float* __restrict__ bfe,
    const float* __restrict__ fc0,
    const float* __restrict__ W0T, const float* __restrict__ W1T,
    const int* __restrict__ ftstart, const unsigned* __restrict__ fpk,
    const uint2* __restrict__ fwh,
    const int* __restrict__ btstart, const unsigned* __restrict__ bpk,
    const uint2* __restrict__ bwh,
    short* __restrict__ Xh96) {
  int lane = threadIdx.x & 63;
  int t = __builtin_amdgcn_readfirstlane(blockIdx.x * 4 + (threadIdx.x >> 6));
  int q = lane >> 4;
  int p = lane & 15;

  auto run_side = [&](const int* st, const unsigned* pkA, const uint2* whA,
                      const float* xA, const float* WT) -> float2 {
    float2 acc = make_float2(0.f, 0.f);
    int s = __builtin_amdgcn_readfirstlane(st[t]);
    int e1 = __builtin_amdgcn_readfirstlane(st[t + 1]);
    int cofs = (q & 1) + (q >> 1) * 8;
    for (int base = s; base < e1; base += 64) {
      int Ln = min(64, e1 - base);
      unsigned mypk = 0;
      uint2 mywh = make_uint2(0u, 0u);
      float4 myx = make_float4(0.f, 0.f, 0.f, 0.f);
      if (lane < Ln) {
        mypk = pkA[base + lane];
        mywh = whA[base + lane];
        myx = *(const float4*)(xA + (size_t)(mypk & 16383) * 4);
      }
      int j = 0;
      for (; j + 3 < Ln; j += 4) {
        unsigned pk_[4];
        float wq_[4], xx_[4], xy_[4], xz_[4], xw_[4];
#pragma unroll
        for (int u = 0; u < 4; u++) {
          pk_[u] = __shfl(mypk, j + u, 64);
          unsigned wlo = __shfl(mywh.x, j + u, 64);
          unsigned whi = __shfl(mywh.y, j + u, 64);
          unsigned wsel = (q < 2) ? wlo : whi;
          wq_[u] = (q & 1) ? b2f_hi(wsel) : b2f_lo(wsel);
          xx_[u] = __shfl(myx.x, j + u, 64);
          xy_[u] = __shfl(myx.y, j + u, 64);
          xz_[u] = __shfl(myx.z, j + u, 64);
          xw_[u] = __shfl(myx.w, j + u, 64);
        }
        float4 A_[4], B_[4];
#pragma unroll
        for (int u = 0; u < 4; u++) {
          int cell = (int)(pk_[u] >> 14) + cofs;
          const float4* Wt = (const float4*)(WT + cell * 128 + p * 8);
          A_[u] = Wt[0];
          B_[u] = Wt[1];
        }
#pragma unroll
        for (int u = 0; u < 4; u++) {
          acc.x = fmaf(wq_[u],
                       xx_[u] * A_[u].x + xy_[u] * A_[u].z + xz_[u] * B_[u].x + xw_[u] * B_[u].z,
                       acc.x);
          acc.y = fmaf(wq_[u],
                       xx_[u] * A_[u].y + xy_[u] * A_[u].w + xz_[u] * B_[u].y + xw_[u] * B_[u].w,
                       acc.y);
        }
      }
      for (; j < Ln; j++) {
        unsigned pk = __shfl(mypk, j, 64);
        unsigned wlo = __shfl(mywh.x, j, 64);
        unsigned whi = __shfl(mywh.y, j, 64);
        unsigned wsel = (q < 2) ? wlo : whi;
        float wq = (q & 1) ? b2f_hi(wsel) : b2f_lo(wsel);
        float xx = __shfl(myx.x, j, 64), xy = __shfl(myx.y, j, 64);
        float xz = __shfl(myx.z, j, 64), xw = __shfl(myx.w, j, 64);
        int cell = (int)(pk >> 14) + cofs;
        const float4* Wt = (const float4*)(WT + cell * 128 + p * 8);
        float4 A = Wt[0], B = Wt[1];
        acc.x = fmaf(wq, xx * A.x + xy * A.z + xz * B.x + xw * B.z, acc.x);
        acc.y = fmaf(wq, xx * A.y + xy * A.w + xz * B.y + xw * B.w, acc.y);
      }
    }
    return acc;
  };

  float2 fa = run_side(ftstart, fpk, fwh, ff, W0T);
  float2 ba = run_side(btstart, bpk, bwh, bfe, W1T);

  fa.x += __shfl_xor(fa.x, 16, 64); fa.y += __shfl_xor(fa.y, 16, 64);
  fa.x += __shfl_xor(fa.x, 32, 64); fa.y += __shfl_xor(fa.y, 32, 64);
  ba.x += __shfl_xor(ba.x, 16, 64); ba.y += __shfl_xor(ba.y, 16, 64);
  ba.x += __shfl_xor(ba.x, 32, 64); ba.y += __shfl_xor(ba.y, 32, 64);
  if (lane < 16) {
    fa.x = fmaxf(fa.x, 0.f); fa.y = fmaxf(fa.y, 0.f);
    *(unsigned*)(Xh96 + (size_t)t * 96 + 32 + 2 * p) = pack2(fa.x, fa.y);
  } else if (lane < 32) {
    ba.x = fmaxf(ba.x, 0.f); ba.y = fmaxf(ba.y, 0.f);
    *(unsigned*)(Xh96 + (size_t)t * 96 + 64 + 2 * p) = pack2(ba.x, ba.y);
  } else if (lane < 48) {
    float4 fv = *(const float4*)(ff + (size_t)t * 4);
    float l0 = fv.x * fc0[2 * p] + fv.y * fc0[32 + 2 * p] +
               fv.z * fc0[64 + 2 * p] + fv.w * fc0[96 + 2 * p];
    float l1 = fv.x * fc0[2 * p + 1] + fv.y * fc0[32 + 2 * p + 1] +
               fv.z * fc0[64 + 2 * p + 1] + fv.w * fc0[96 + 2 * p + 1];
    l0 = fmaxf(l0, 0.f); l1 = fmaxf(l1, 0.f);
    *(unsigned*)(Xh96 + (size_t)t * 96 + 2 * p) = pack2(l0, l1);
  }
}

// ---------------------------------------------------------------------------
// Phase B stages 2/3. FULL=1: CC==64 single pass — no cell-window check, no
// c0, unconditional gathers, no fp32 carry (init&&fin). FULL=0: generic
// chunked fallback. (256,4) — measured best.
// ---------------------------------------------------------------------------
template <int CIN, int RESID, int FULL>
__global__ void __launch_bounds__(256, 4) b23(
    const short* __restrict__ xin, const float* __restrict__ fc,
    const int* __restrict__ ftstart, const unsigned* __restrict__ epk,
    const uint2* __restrict__ ewh, const short* __restrict__ Y,
    const short* __restrict__ resid, float* __restrict__ dest,
    short* __restrict__ Xh64, int c0, int CC, int init, int fin) {
  int lane = threadIdx.x & 63;
  int t = __builtin_amdgcn_readfirstlane(blockIdx.x * 4 + (threadIdx.x >> 6));
  int q = lane >> 4;
  int sub = lane & 15;
  int cofs = (q & 1) + (q >> 1) * 8;
  const int YWl = FULL ? 4096 : CC * 64;
  float a0 = 0.f, a1 = 0.f, a2 = 0.f, a3 = 0.f;
  if (FULL || init) {
    constexpr int KQ = CIN / 4;
    const unsigned* xr32 = (const unsigned*)(xin + (size_t)t * CIN) + q * (KQ / 2);
#pragma unroll
    for (int kk = 0; kk < KQ / 2; kk++) {
      unsigned uu = xr32[kk];
      int k = q * KQ + 2 * kk;
      float xlo = b2f_lo(uu), xhi = b2f_hi(uu);
      float4 f0 = *(const float4*)(fc + (size_t)k * 64 + 4 * sub);
      float4 f1 = *(const float4*)(fc + (size_t)(k + 1) * 64 + 4 * sub);
      a0 = fmaf(xlo, f0.x, a0); a1 = fmaf(xlo, f0.y, a1);
      a2 = fmaf(xlo, f0.z, a2); a3 = fmaf(xlo, f0.w, a3);
      a0 = fmaf(xhi, f1.x, a0); a1 = fmaf(xhi, f1.y, a1);
      a2 = fmaf(xhi, f1.z, a2); a3 = fmaf(xhi, f1.w, a3);
    }
  }
  int s = __builtin_amdgcn_readfirstlane(ftstart[t]);
  int e1 = __builtin_amdgcn_readfirstlane(ftstart[t + 1]);
  for (int base = s; base < e1; base += 64) {
    int Ln = min(64, e1 - base);
    unsigned mypk = 0;
    uint2 mywh = make_uint2(0u, 0u);
    if (lane < Ln) {
      mypk = epk[base + lane];
      mywh = ewh[base + lane];
    }
    int j = 0;
    for (; j + 7 < Ln; j += 8) {
      float wq_[8];
      uint2 r_[8];
#pragma unroll
      for (int u = 0; u < 8; u++) {
        unsigned pk = __shfl(mypk, j + u, 64);
        unsigned wlo = __shfl(mywh.x, j + u, 64);
        unsigned whi = __shfl(mywh.y, j + u, 64);
        unsigned wsel = (q < 2) ? wlo : whi;
        wq_[u] = (q & 1) ? b2f_hi(wsel) : b2f_lo(wsel);
        int src = pk & 16383;
        int cell = (int)(pk >> 14) + cofs - (FULL ? 0 : c0);
        if (FULL) {
          r_[u] = *(const uint2*)(Y + (size_t)src * 4096 + cell * 64 + 4 * sub);
        } else {
          r_[u] = make_uint2(0, 0);
          if ((unsigned)cell < (unsigned)CC)
            r_[u] = *(const uint2*)(Y + (size_t)src * YWl + cell * 64 + 4 * sub);
        }
      }
#pragma unroll
      for (int u = 0; u < 8; u++) {
        a0 = fmaf(wq_[u], b2f_lo(r_[u].x), a0);
        a1 = fmaf(wq_[u], b2f_hi(r_[u].x), a1);
        a2 = fmaf(wq_[u], b2f_lo(r_[u].y), a2);
        a3 = fmaf(wq_[u], b2f_hi(r_[u].y), a3);
      }
    }
    for (; j < Ln; j++) {
      unsigned pk = __shfl(mypk, j, 64);
      unsigned wlo = __shfl(mywh.x, j, 64);
      unsigned whi = __shfl(mywh.y, j, 64);
      unsigned wsel = (q < 2) ? wlo : whi;
      float wq = (q & 1) ? b2f_hi(wsel) : b2f_lo(wsel);
      int src = pk & 16383;
      int cell = (int)(pk >> 14) + cofs - (FULL ? 0 : c0);
      if (FULL || (unsigned)cell < (unsigned)CC) {
        uint2 r = *(const uint2*)(Y + (size_t)src * YWl + cell * 64 + 4 * sub);
        a0 = fmaf(wq, b2f_lo(r.x), a0);
        a1 = fmaf(wq, b2f_hi(r.x), a1);
        a2 = fmaf(wq, b2f_lo(r.y), a2);
        a3 = fmaf(wq, b2f_hi(r.y), a3);
      }
    }
  }
  a0 += __shfl_xor(a0, 16, 64); a1 += __shfl_xor(a1, 16, 64);
  a2 += __shfl_xor(a2, 16, 64); a3 += __shfl_xor(a3, 16, 64);
  a0 += __shfl_xor(a0, 32, 64); a1 += __shfl_xor(a1, 32, 64);
  a2 += __shfl_xor(a2, 32, 64); a3 += __shfl_xor(a3, 32, 64);
  if (lane < 16) {
    if (!FULL && !init) {
      float4 d = *(const float4*)(dest + (size_t)t * 64 + 4 * sub);
      a0 += d.x; a1 += d.y; a2 += d.z; a3 += d.w;
    }
    if (RESID && (FULL || init)) {
      uint2 rr = *(const uint2*)(resid + (size_t)t * 64 + 4 * sub);
      a0 += b2f_lo(rr.x); a1 += b2f_hi(rr.x);
      a2 += b2f_lo(rr.y); a3 += b2f_hi(rr.y);
    }
    if (FULL || fin) {
      a0 = fmaxf(a0, 0.f); a1 = fmaxf(a1, 0.f);
      a2 = fmaxf(a2, 0.f); a3 = fmaxf(a3, 0.f);
      uint2 pkd = make_uint2(pack2(a0, a1), pack2(a2, a3));
      *(uint2*)(Xh64 + (size_t)t * 64 + 4 * sub) = pkd;
    } else {
      *(float4*)(dest + (size_t)t * 64 + 4 * sub) = make_float4(a0, a1, a2, a3);
    }
  }
}

// ---------------------------------------------------------------------------
// Phase B stage 4: out[t] = gather(bf16 Y4h[NF][128]) + bf16(ans2)@fc3.
// ---------------------------------------------------------------------------
__global__ void __launch_bounds__(256, 8) b4_stage4(
    const short* __restrict__ Xh64b, const float* __restrict__ fc3,
    const int* __restrict__ ftstart, const unsigned* __restrict__ epk,
    const uint2* __restrict__ ewh, const short* __restrict__ Y4h,
    float* __restrict__ outp) {
  int lane = threadIdx.x & 63;
  int t = blockIdx.x * 4 + (threadIdx.x >> 6);
  int s4 = ftstart[t] * 4, e4 = ftstart[t + 1] * 4;
  float m0 = 0.f, m1 = 0.f;
  for (int fq = s4 + lane; fq < e4; fq += 64) {
    int idx = fq >> 2, j = fq & 3;
    unsigned pk = epk[idx];
    uint2 wh = ewh[idx];
    int src = pk & 16383;
    int cell = (int)(pk >> 14) + (j & 1) + (j >> 1) * 8;
    unsigned wsel = (j < 2) ? wh.x : wh.y;
    float w = (j & 1) ? b2f_hi(wsel) : b2f_lo(wsel);
    unsigned mm = *(const unsigned*)(Y4h + (size_t)src * 128 + cell * 2);
    m0 = fmaf(w, b2f_lo(mm), m0);
    m1 = fmaf(w, b2f_hi(mm), m1);
  }
  {
    float a = b2fs(Xh64b[(size_t)t * 64 + lane]);
    m0 += a * fc3[lane * 2 + 0];
    m1 += a * fc3[lane * 2 + 1];
  }
#pragma unroll
  for (int off = 32; off > 0; off >>= 1) {
    m0 += __shfl_xor(m0, off, 64);
    m1 += __shfl_xor(m1, off, 64);
  }
  if (lane == 0) {
    outp[t * 2] = m0;
    outp[t * 2 + 1] = m1;
  }
}

// ---------------------------------------------------------------------------
extern "C" void kernel_launch(void* const* d_in, const int* in_sizes, int n_in,
                              void* d_out, int out_size, void* d_ws, size_t ws_size,
                              hipStream_t stream) {
  const float* fp  = (const float*)d_in[0];
  const float* bp  = (const float*)d_in[1];
  const float* ff  = (const float*)d_in[2];
  const float* bfe = (const float*)d_in[3];
  const float* sup = (const float*)d_in[4];
  const int* fi  = (const int*)d_in[5];
  const int* fj  = (const int*)d_in[6];
  const int* bfi = (const int*)d_in[7];
  const int* bb  = (const int*)d_in[8];
  const float* W0 = (const float*)d_in[9];
  const float* W1 = (const float*)d_in[10];
  const float* W2 = (const float*)d_in[11];
  const float* W3 = (const float*)d_in[12];
  const float* W4 = (const float*)d_in[13];
  const float* fc0 = (const float*)d_in[14];
  const float* fc1 = (const float*)d_in[15];
  const float* fc2 = (const float*)d_in[16];
  const float* fc3 = (const float*)d_in[17];
  float* out = (float*)d_out;

  char* w = (char*)d_ws;
  size_t off = 0;
  auto alloc = [&](size_t bytes) {
    char* p = w + off;
    off += (bytes + 255) & ~size_t(255);
    return p;
  };
  float* ans1   = (float*)alloc((size_t)NF * 64 * 4);   // fallback carry only
  float* ans2   = (float*)alloc((size_t)NF * 64 * 4);   // fallback carry only
  int* fthist  = (int*)alloc((size_t)NF * 4);
  int* bthist  = (int*)alloc((size_t)NF * 4);   // adjacent to fthist: one memset
  int* ftstart = (int*)alloc((size_t)(NF + 1) * 4);
  int* ftcur   = (int*)alloc((size_t)NF * 4);
  int* btstart = (int*)alloc((size_t)(NF + 1) * 4);
  int* btcur   = (int*)alloc((size_t)NF * 4);
  unsigned* fpk  = (unsigned*)alloc((size_t)EF * 4);
  uint2* fwh     = (uint2*)alloc((size_t)EF * 8);
  unsigned* bpk  = (unsigned*)alloc((size_t)EB * 4);
  uint2* bwh     = (uint2*)alloc((size_t)EB * 8);
  short* Xh96  = (short*)alloc((size_t)NF * 96 * 2);
  short* Xh64  = (short*)alloc((size_t)NF * 64 * 2);   // bf16 ans1
  short* Xh64b = (short*)alloc((size_t)NF * 64 * 2);   // bf16 ans2
  short* BT2 = (short*)alloc((size_t)4096 * 96 * 2);
  short* BT3 = (short*)alloc((size_t)4096 * 64 * 2);
  short* BT4 = (short*)alloc((size_t)128 * 64 * 2);
  float* W0T = (float*)alloc((size_t)8192 * 4);
  float* W1T = (float*)alloc((size_t)8192 * 4);
  char* Yreg = w + off;
  size_t avail = (ws_size > off) ? (ws_size - off) : 0;
  size_t percell = (size_t)NF * 64 * 2;
  int CC = 64;
  while (CC > 8 && (size_t)CC * percell > avail) CC >>= 1;
  int S = 64 / CC;
  short* Y   = (short*)Yreg;
  short* Y4h = (short*)Yreg;  // [NF][128] bf16, 4MB (reuses Y region)

  hipMemsetAsync(fthist, 0, (size_t)NF * 8, stream);

  build_weights<<<2624, 256, 0, stream>>>(W2, W3, W4, W0, W1, BT2, BT3, BT4, W0T, W1T);
  dual_hist<<<FBLK + BBLK, 256, 0, stream>>>(fi, bfi, fthist, bthist);
  csr_scan2<<<2, 1024, 0, stream>>>(fthist, bthist, ftstart, ftcur, btstart, btcur);
  dual_scatter_payload<<<FBLK + BBLK, 256, 0, stream>>>(fi, fj, bfi, bb, fp, bp, sup,
                                                        ftcur, btcur, fpk, fwh, bpk, bwh);

  // Stage 1: lane-parallel fused, 1 wave/node. Emits bf16 Xh96 only.
  b1_stage1<<<NF / 4, 256, 0, stream>>>(ff, bfe, fc0, W0T, W1T,
                                        ftstart, fpk, fwh, btstart, bpk, bwh, Xh96);
  if (S == 1) {
    // Fast path: CC=64, single pass per stage — FULL kernels (no window
    // checks, no fp32 carry).
    gemm_bf16<96><<<dim3(NF / 128, 32), 256, 0, stream>>>(Xh96, BT2, Y, 4096);
    b23<96, 0, 1><<<NF / 4, 256, 0, stream>>>(Xh96, fc1, ftstart, fpk, fwh,
                                              Y, nullptr, ans1, Xh64, 0, 64, 1, 1);
    gemm_bf16<64><<<dim3(NF / 128, 32), 256, 0, stream>>>(Xh64, BT3, Y, 4096);
    b23<64, 1, 1><<<NF / 4, 256, 0, stream>>>(Xh64, fc2, ftstart, fpk, fwh,
                                              Y, Xh64, ans2, Xh64b, 0, 64, 1, 1);
  } else {
    // Generic chunked fallback (small workspace).
    for (int c = 0; c < S; c++) {
      int c0 = c * CC;
      gemm_bf16<96><<<dim3(NF / 128, CC * 64 / 128), 256, 0, stream>>>(
          Xh96, BT2 + (size_t)c0 * 64 * 96, Y, CC * 64);
      b23<96, 0, 0><<<NF / 4, 256, 0, stream>>>(Xh96, fc1, ftstart, fpk, fwh,
                                                Y, nullptr, ans1, Xh64,
                                                c0, CC, c == 0, c == S - 1);
    }
    for (int c = 0; c < S; c++) {
      int c0 = c * CC;
      gemm_bf16<64><<<dim3(NF / 128, CC * 64 / 128), 256, 0, stream>>>(
          Xh64, BT3 + (size_t)c0 * 64 * 64, Y, CC * 64);
      b23<64, 1, 0><<<NF / 4, 256, 0, stream>>>(Xh64, fc2, ftstart, fpk, fwh,
                                                Y, Xh64, ans2, Xh64b,
                                                c0, CC, c == 0, c == S - 1);
    }
  }
  // Stage 4: W4 conv as a single MFMA GEMM [NF x 64] @ [64 x 128], then gather.
  gemm_bf16<64><<<dim3(NF / 128, 1), 256, 0, stream>>>(Xh64b, BT4, Y4h, 128);
  b4_stage4<<<NF / 4, 256, 0, stream>>>(Xh64b, fc3, ftstart, fpk, fwh, Y4h, out);
}

// Round 20
// 289.248 us; speedup vs baseline: 1.3704x; 1.0118x over previous
//
#include <hip/hip_runtime.h>

#define NF 16384
#define NB 4096
#define EF 262144
#define EB 65536
#define FBLK 1024   // EF/256
#define BBLK 256    // EB/256

typedef __attribute__((ext_vector_type(8))) short bf16x8;
typedef __attribute__((ext_vector_type(4))) float f32x4;

__device__ __forceinline__ short f2b(float f) {
  unsigned u = __float_as_uint(f);
  u += 0x7fff + ((u >> 16) & 1);   // RNE
  return (short)(u >> 16);
}
__device__ __forceinline__ unsigned pack2(float lo, float hi) {
  return (unsigned)(unsigned short)f2b(lo) | ((unsigned)(unsigned short)f2b(hi) << 16);
}
__device__ __forceinline__ float b2f_lo(unsigned u) {
  return __uint_as_float(u << 16);
}
__device__ __forceinline__ float b2f_hi(unsigned u) {
  return __uint_as_float(u & 0xffff0000u);
}
__device__ __forceinline__ float b2fs(short s) {
  return __uint_as_float(((unsigned)(unsigned short)s) << 16);
}

// ---------------------------------------------------------------------------
// Merged prep: blocks 0..1279 = target histograms; 1280..3903 = all weight
// tables (BT2/BT3/BT4/W0T/W1T). Independent workloads, one launch.
// ---------------------------------------------------------------------------
__global__ void __launch_bounds__(256) prep_all(
    const int* __restrict__ fi, const int* __restrict__ bfi,
    int* __restrict__ fhist, int* __restrict__ bhist,
    const float* __restrict__ W2, const float* __restrict__ W3,
    const float* __restrict__ W4, const float* __restrict__ W0,
    const float* __restrict__ W1,
    short* __restrict__ BT2, short* __restrict__ BT3, short* __restrict__ BT4,
    float* __restrict__ W0T, float* __restrict__ W1T) {
  int bid = blockIdx.x;
  if (bid < FBLK) {
    int e = bid * 256 + threadIdx.x;
    atomicAdd(fhist + fi[e], 1);
    return;
  }
  if (bid < FBLK + BBLK) {
    int e = (bid - FBLK) * 256 + threadIdx.x;
    atomicAdd(bhist + bfi[e], 1);
    return;
  }
  int wb = bid - (FBLK + BBLK);
  if (wb < 1536) {                       // BT2: 393216 elems
    int tid = wb * 256 + threadIdx.x;
    int k = tid % 96, n = tid / 96;
    BT2[tid] = f2b(W2[((size_t)(n >> 6) * 96 + k) * 64 + (n & 63)]);
  } else if (wb < 2560) {                // BT3: 262144 elems
    int tid = (wb - 1536) * 256 + threadIdx.x;
    int k = tid & 63, n = tid >> 6;
    BT3[tid] = f2b(W3[((size_t)(n >> 6) * 64 + k) * 64 + (n & 63)]);
  } else if (wb < 2592) {                // BT4: 8192 elems
    int tid = (wb - 2560) * 256 + threadIdx.x;
    int k = tid & 63, n = tid >> 6;
    BT4[tid] = f2b(W4[((size_t)(n >> 1) * 64 + k) * 2 + (n & 1)]);
  } else {                               // W0T/W1T: 8192 elems each
    int tid = (wb - 2592) * 256 + threadIdx.x;
    int cell = tid >> 7, r = tid & 127;
    int p = r >> 3, k = (r >> 1) & 3, c = r & 1;
    int dst = cell * 128 + p * 8 + k * 2 + c;
    int src = cell * 128 + k * 32 + 2 * p + c;
    W0T[dst] = W0[src];
    W1T[dst] = W1[src];
  }
}

__global__ void __launch_bounds__(1024) csr_scan2(const int* __restrict__ fhist,
                                                  const int* __restrict__ bhist,
                                                  int* __restrict__ fstart, int* __restrict__ fcur,
                                                  int* __restrict__ bstart, int* __restrict__ bcur) {
  const int* hist = blockIdx.x ? bhist : fhist;
  int* start = blockIdx.x ? bstart : fstart;
  int* cursor = blockIdx.x ? bcur : fcur;
  __shared__ int wtot[16];
  int t = threadIdx.x;
  int lane = t & 63, wv = t >> 6;
  int base = t * 16;
  int vals[16];
  int s = 0;
#pragma unroll
  for (int k = 0; k < 16; k++) { vals[k] = hist[base + k]; s += vals[k]; }
  int ss = s;
  for (int off = 1; off < 64; off <<= 1) {
    int o = __shfl_up(ss, off, 64);
    if (lane >= off) ss += o;
  }
  if (lane == 63) wtot[wv] = ss;
  __syncthreads();
  if (t < 16) {
    int v = wtot[t];
    int vv = v;
    for (int off = 1; off < 16; off <<= 1) {
      int o = __shfl_up(vv, off, 64);
      if (t >= off) vv += o;
    }
    wtot[t] = vv - v;
  }
  __syncthreads();
  int run = ss - s + wtot[wv];
#pragma unroll
  for (int k = 0; k < 16; k++) { start[base + k] = run; cursor[base + k] = run; run += vals[k]; }
  if (t == 1023) start[16384] = run;
}

// ---------------------------------------------------------------------------
// Merged scatter + payload + tent-basis. Payload: pk (4B) + 4xbf16 wts (8B).
// ---------------------------------------------------------------------------
__global__ void __launch_bounds__(256) dual_scatter_payload(
    const int* __restrict__ fi, const int* __restrict__ fj,
    const int* __restrict__ bfi, const int* __restrict__ bb,
    const float* __restrict__ fp, const float* __restrict__ bp,
    const float* __restrict__ supportp,
    int* __restrict__ fcur, int* __restrict__ bcur,
    unsigned* __restrict__ fpk, uint2* __restrict__ fwh,
    unsigned* __restrict__ bpk, uint2* __restrict__ bwh) {
  int bid = blockIdx.x;
  bool fluid = bid < FBLK;
  int e = (fluid ? bid : bid - FBLK) * 256 + threadIdx.x;
  int ti = fluid ? fi[e] : bfi[e];
  int si = fluid ? fj[e] : bb[e];
  const float2* pT2 = (const float2*)fp;
  const float2* pS2 = fluid ? (const float2*)fp : (const float2*)bp;
  float sign = fluid ? -1.f : 1.f;
  float inv_sup = 1.0f / supportp[0];
  float2 pt = pT2[ti];
  float2 ps = pS2[si];
  // d = sign*(src-tgt)/support. (-1)*(+0) = -0 preserves reference signed
  // zeros for self-edges (atan2(-0,-0) = -pi).
  float dx = sign * ((ps.x - pt.x) * inv_sup);
  float dy = sign * ((ps.y - pt.y) * inv_sup);
  dx = fminf(fmaxf(dx, -1.f), 1.f);
  dy = fminf(fmaxf(dy, -1.f), 1.f);
  float r = sqrtf(dx * dx + dy * dy + 1e-12f);
  float theta;
  if (dx == 0.0f && dy == 0.0f) {
    float mag = __builtin_signbitf(dx) ? 3.14159265358979323846f : 0.0f;
    theta = __builtin_signbitf(dy) ? -mag : mag;
  } else {
    theta = atan2f(dy, dx);
  }
  float u = 2.f * r - 1.f;
  float v = theta * (1.f / 3.14159265358979323846f);
  float tu = (u + 1.f) * 3.5f;
  float tv = (v + 1.f) * 3.5f;
  int iu = min(max((int)floorf(tu), 0), 6);
  int iv = min(max((int)floorf(tv), 0), 6);
  float wu0 = fmaxf(0.f, 1.f - fabsf(tu - (float)iu));
  float wu1 = fmaxf(0.f, 1.f - fabsf(tu - (float)(iu + 1)));
  float wv0 = fmaxf(0.f, 1.f - fabsf(tv - (float)iv));
  float wv1 = fmaxf(0.f, 1.f - fabsf(tv - (float)(iv + 1)));
  unsigned pk = (unsigned)si | ((unsigned)(iu * 8 + iv) << 14);
  uint2 wh = make_uint2(pack2(wu0 * wv0, wu0 * wv1), pack2(wu1 * wv0, wu1 * wv1));
  if (fluid) {
    int p = atomicAdd(fcur + ti, 1);
    fpk[p] = pk; fwh[p] = wh;
  } else {
    int p = atomicAdd(bcur + ti, 1);
    bpk[p] = pk; bwh[p] = wh;
  }
}

// ---------------------------------------------------------------------------
// Dense MFMA GEMM, LDS-staged tiles (conflict-free padded rows, 16B aligned).
// ---------------------------------------------------------------------------
template <int K>
__global__ void __launch_bounds__(256, 2) gemm_bf16(
    const short* __restrict__ A, const short* __restrict__ BT,
    short* __restrict__ C, int N) {
  constexpr int KP = K + 8;
  __shared__ __align__(16) short Al[128 * KP];
  __shared__ __align__(16) short Bl[128 * KP];
  int tid = threadIdx.x;
  int lane = tid & 63;
  int w = tid >> 6;
  int m0b = blockIdx.x * 128;
  int n0b = blockIdx.y * 128;
  constexpr int ROWV = K / 8;
  for (int f = tid; f < 128 * ROWV; f += 256) {
    int r = f / ROWV, c = f % ROWV;
    *(float4*)(Al + r * KP + c * 8) = *(const float4*)(A + (size_t)(m0b + r) * K + c * 8);
    *(float4*)(Bl + r * KP + c * 8) = *(const float4*)(BT + (size_t)(n0b + r) * K + c * 8);
  }
  __syncthreads();
  int m0 = (w & 1) * 64;
  int n0 = (w >> 1) * 64;
  int fr = lane & 15;
  int kg = lane >> 4;
  f32x4 acc[4][4] = {};
#pragma unroll
  for (int kc = 0; kc < K; kc += 32) {
    bf16x8 a[4], b[4];
#pragma unroll
    for (int i = 0; i < 4; i++) {
      a[i] = *(const bf16x8*)(Al + (m0 + i * 16 + fr) * KP + kc + kg * 8);
      b[i] = *(const bf16x8*)(Bl + (n0 + i * 16 + fr) * KP + kc + kg * 8);
    }
#pragma unroll
    for (int i = 0; i < 4; i++)
#pragma unroll
      for (int j = 0; j < 4; j++)
        acc[i][j] = __builtin_amdgcn_mfma_f32_16x16x32_bf16(a[i], b[j], acc[i][j], 0, 0, 0);
  }
#pragma unroll
  for (int i = 0; i < 4; i++) {
    int row = m0b + m0 + i * 16 + (lane >> 4) * 4;
#pragma unroll
    for (int j = 0; j < 4; j++) {
      int col = n0b + n0 + j * 16 + (lane & 15);
#pragma unroll
      for (int r = 0; r < 4; r++)
        C[(size_t)(row + r) * N + col] = f2b(acc[i][j][r]);
    }
  }
}

// ---------------------------------------------------------------------------
// Stage 1, lane-parallel payload + 4-edge unrolled broadcast loop (W0T/W1T).
// Writes ONLY bf16 Xh96.
// ---------------------------------------------------------------------------
__global__ void __launch_bounds__(256, 8) b1_stage1(
    const float* __restrict__ ff, const float* __restrict__ bfe,
    const float* __restrict__ fc0,
    const float* __restrict__ W0T, const float* __restrict__ W1T,
    const int* __restrict__ ftstart, const unsigned* __restrict__ fpk,
    const uint2* __restrict__ fwh,
    const int* __restrict__ btstart, const unsigned* __restrict__ bpk,
    const uint2* __restrict__ bwh,
    short* __restrict__ Xh96) {
  int lane = threadIdx.x & 63;
  int t = __builtin_amdgcn_readfirstlane(blockIdx.x * 4 + (threadIdx.x >> 6));
  int q = lane >> 4;
  int p = lane & 15;

  auto run_side = [&](const int* st, const unsigned* pkA, const uint2* whA,
                      const float* xA, const float* WT) -> float2 {
    float2 acc = make_float2(0.f, 0.f);
    int s = __builtin_amdgcn_readfirstlane(st[t]);
    int e1 = __builtin_amdgcn_readfirstlane(st[t + 1]);
    int cofs = (q & 1) + (q >> 1) * 8;
    for (int base = s; base < e1; base += 64) {
      int Ln = min(64, e1 - base);
      unsigned mypk = 0;
      uint2 mywh = make_uint2(0u, 0u);
      float4 myx = make_float4(0.f, 0.f, 0.f, 0.f);
      if (lane < Ln) {
        mypk = pkA[base + lane];
        mywh = whA[base + lane];
        myx = *(const float4*)(xA + (size_t)(mypk & 16383) * 4);
      }
      int j = 0;
      for (; j + 3 < Ln; j += 4) {
        unsigned pk_[4];
        float wq_[4], xx_[4], xy_[4], xz_[4], xw_[4];
#pragma unroll
        for (int u = 0; u < 4; u++) {
          pk_[u] = __shfl(mypk, j + u, 64);
          unsigned wlo = __shfl(mywh.x, j + u, 64);
          unsigned whi = __shfl(mywh.y, j + u, 64);
          unsigned wsel = (q < 2) ? wlo : whi;
          wq_[u] = (q & 1) ? b2f_hi(wsel) : b2f_lo(wsel);
          xx_[u] = __shfl(myx.x, j + u, 64);
          xy_[u] = __shfl(myx.y, j + u, 64);
          xz_[u] = __shfl(myx.z, j + u, 64);
          xw_[u] = __shfl(myx.w, j + u, 64);
        }
        float4 A_[4], B_[4];
#pragma unroll
        for (int u = 0; u < 4; u++) {
          int cell = (int)(pk_[u] >> 14) + cofs;
          const float4* Wt = (const float4*)(WT + cell * 128 + p * 8);
          A_[u] = Wt[0];
          B_[u] = Wt[1];
        }
#pragma unroll
        for (int u = 0; u < 4; u++) {
          acc.x = fmaf(wq_[u],
                       xx_[u] * A_[u].x + xy_[u] * A_[u].z + xz_[u] * B_[u].x + xw_[u] * B_[u].z,
                       acc.x);
          acc.y = fmaf(wq_[u],
                       xx_[u] * A_[u].y + xy_[u] * A_[u].w + xz_[u] * B_[u].y + xw_[u] * B_[u].w,
                       acc.y);
        }
      }
      for (; j < Ln; j++) {
        unsigned pk = __shfl(mypk, j, 64);
        unsigned wlo = __shfl(mywh.x, j, 64);
        unsigned whi = __shfl(mywh.y, j, 64);
        unsigned wsel = (q < 2) ? wlo : whi;
        float wq = (q & 1) ? b2f_hi(wsel) : b2f_lo(wsel);
        float xx = __shfl(myx.x, j, 64), xy = __shfl(myx.y, j, 64);
        float xz = __shfl(myx.z, j, 64), xw = __shfl(myx.w, j, 64);
        int cell = (int)(pk >> 14) + cofs;
        const float4* Wt = (const float4*)(WT + cell * 128 + p * 8);
        float4 A = Wt[0], B = Wt[1];
        acc.x = fmaf(wq, xx * A.x + xy * A.z + xz * B.x + xw * B.z, acc.x);
        acc.y = fmaf(wq, xx * A.y + xy * A.w + xz * B.y + xw * B.w, acc.y);
      }
    }
    return acc;
  };

  float2 fa = run_side(ftstart, fpk, fwh, ff, W0T);
  float2 ba = run_side(btstart, bpk, bwh, bfe, W1T);

  fa.x += __shfl_xor(fa.x, 16, 64); fa.y += __shfl_xor(fa.y, 16, 64);
  fa.x += __shfl_xor(fa.x, 32, 64); fa.y += __shfl_xor(fa.y, 32, 64);
  ba.x += __shfl_xor(ba.x, 16, 64); ba.y += __shfl_xor(ba.y, 16, 64);
  ba.x += __shfl_xor(ba.x, 32, 64); ba.y += __shfl_xor(ba.y, 32, 64);
  if (lane < 16) {
    fa.x = fmaxf(fa.x, 0.f); fa.y = fmaxf(fa.y, 0.f);
    *(unsigned*)(Xh96 + (size_t)t * 96 + 32 + 2 * p) = pack2(fa.x, fa.y);
  } else if (lane < 32) {
    ba.x = fmaxf(ba.x, 0.f); ba.y = fmaxf(ba.y, 0.f);
    *(unsigned*)(Xh96 + (size_t)t * 96 + 64 + 2 * p) = pack2(ba.x, ba.y);
  } else if (lane < 48) {
    float4 fv = *(const float4*)(ff + (size_t)t * 4);
    float l0 = fv.x * fc0[2 * p] + fv.y * fc0[32 + 2 * p] +
               fv.z * fc0[64 + 2 * p] + fv.w * fc0[96 + 2 * p];
    float l1 = fv.x * fc0[2 * p + 1] + fv.y * fc0[32 + 2 * p + 1] +
               fv.z * fc0[64 + 2 * p + 1] + fv.w * fc0[96 + 2 * p + 1];
    l0 = fmaxf(l0, 0.f); l1 = fmaxf(l1, 0.f);
    *(unsigned*)(Xh96 + (size_t)t * 96 + 2 * p) = pack2(l0, l1);
  }
}

// ---------------------------------------------------------------------------
// Phase B stages 2/3. FULL=1: CC==64 single pass — no window check, no fp32
// carry. FULL=0: generic chunked fallback. (256,4) — measured best.
// ---------------------------------------------------------------------------
template <int CIN, int RESID, int FULL>
__global__ void __launch_bounds__(256, 4) b23(
    const short* __restrict__ xin, const float* __restrict__ fc,
    const int* __restrict__ ftstart, const unsigned* __restrict__ epk,
    const uint2* __restrict__ ewh, const short* __restrict__ Y,
    const short* __restrict__ resid, float* __restrict__ dest,
    short* __restrict__ Xh64, int c0, int CC, int init, int fin) {
  int lane = threadIdx.x & 63;
  int t = __builtin_amdgcn_readfirstlane(blockIdx.x * 4 + (threadIdx.x >> 6));
  int q = lane >> 4;
  int sub = lane & 15;
  int cofs = (q & 1) + (q >> 1) * 8;
  const int YWl = FULL ? 4096 : CC * 64;
  float a0 = 0.f, a1 = 0.f, a2 = 0.f, a3 = 0.f;
  if (FULL || init) {
    constexpr int KQ = CIN / 4;
    const unsigned* xr32 = (const unsigned*)(xin + (size_t)t * CIN) + q * (KQ / 2);
#pragma unroll
    for (int kk = 0; kk < KQ / 2; kk++) {
      unsigned uu = xr32[kk];
      int k = q * KQ + 2 * kk;
      float xlo = b2f_lo(uu), xhi = b2f_hi(uu);
      float4 f0 = *(const float4*)(fc + (size_t)k * 64 + 4 * sub);
      float4 f1 = *(const float4*)(fc + (size_t)(k + 1) * 64 + 4 * sub);
      a0 = fmaf(xlo, f0.x, a0); a1 = fmaf(xlo, f0.y, a1);
      a2 = fmaf(xlo, f0.z, a2); a3 = fmaf(xlo, f0.w, a3);
      a0 = fmaf(xhi, f1.x, a0); a1 = fmaf(xhi, f1.y, a1);
      a2 = fmaf(xhi, f1.z, a2); a3 = fmaf(xhi, f1.w, a3);
    }
  }
  int s = __builtin_amdgcn_readfirstlane(ftstart[t]);
  int e1 = __builtin_amdgcn_readfirstlane(ftstart[t + 1]);
  for (int base = s; base < e1; base += 64) {
    int Ln = min(64, e1 - base);
    unsigned mypk = 0;
    uint2 mywh = make_uint2(0u, 0u);
    if (lane < Ln) {
      mypk = epk[base + lane];
      mywh = ewh[base + lane];
    }
    int j = 0;
    for (; j + 7 < Ln; j += 8) {
      float wq_[8];
      uint2 r_[8];
#pragma unroll
      for (int u = 0; u < 8; u++) {
        unsigned pk = __shfl(mypk, j + u, 64);
        unsigned wlo = __shfl(mywh.x, j + u, 64);
        unsigned whi = __shfl(mywh.y, j + u, 64);
        unsigned wsel = (q < 2) ? wlo : whi;
        wq_[u] = (q & 1) ? b2f_hi(wsel) : b2f_lo(wsel);
        int src = pk & 16383;
        int cell = (int)(pk >> 14) + cofs - (FULL ? 0 : c0);
        if (FULL) {
          r_[u] = *(const uint2*)(Y + (size_t)src * 4096 + cell * 64 + 4 * sub);
        } else {
          r_[u] = make_uint2(0, 0);
          if ((unsigned)cell < (unsigned)CC)
            r_[u] = *(const uint2*)(Y + (size_t)src * YWl + cell * 64 + 4 * sub);
        }
      }
#pragma unroll
      for (int u = 0; u < 8; u++) {
        a0 = fmaf(wq_[u], b2f_lo(r_[u].x), a0);
        a1 = fmaf(wq_[u], b2f_hi(r_[u].x), a1);
        a2 = fmaf(wq_[u], b2f_lo(r_[u].y), a2);
        a3 = fmaf(wq_[u], b2f_hi(r_[u].y), a3);
      }
    }
    for (; j < Ln; j++) {
      unsigned pk = __shfl(mypk, j, 64);
      unsigned wlo = __shfl(mywh.x, j, 64);
      unsigned whi = __shfl(mywh.y, j, 64);
      unsigned wsel = (q < 2) ? wlo : whi;
      float wq = (q & 1) ? b2f_hi(wsel) : b2f_lo(wsel);
      int src = pk & 16383;
      int cell = (int)(pk >> 14) + cofs - (FULL ? 0 : c0);
      if (FULL || (unsigned)cell < (unsigned)CC) {
        uint2 r = *(const uint2*)(Y + (size_t)src * YWl + cell * 64 + 4 * sub);
        a0 = fmaf(wq, b2f_lo(r.x), a0);
        a1 = fmaf(wq, b2f_hi(r.x), a1);
        a2 = fmaf(wq, b2f_lo(r.y), a2);
        a3 = fmaf(wq, b2f_hi(r.y), a3);
      }
    }
  }
  a0 += __shfl_xor(a0, 16, 64); a1 += __shfl_xor(a1, 16, 64);
  a2 += __shfl_xor(a2, 16, 64); a3 += __shfl_xor(a3, 16, 64);
  a0 += __shfl_xor(a0, 32, 64); a1 += __shfl_xor(a1, 32, 64);
  a2 += __shfl_xor(a2, 32, 64); a3 += __shfl_xor(a3, 32, 64);
  if (lane < 16) {
    if (!FULL && !init) {
      float4 d = *(const float4*)(dest + (size_t)t * 64 + 4 * sub);
      a0 += d.x; a1 += d.y; a2 += d.z; a3 += d.w;
    }
    if (RESID && (FULL || init)) {
      uint2 rr = *(const uint2*)(resid + (size_t)t * 64 + 4 * sub);
      a0 += b2f_lo(rr.x); a1 += b2f_hi(rr.x);
      a2 += b2f_lo(rr.y); a3 += b2f_hi(rr.y);
    }
    if (FULL || fin) {
      a0 = fmaxf(a0, 0.f); a1 = fmaxf(a1, 0.f);
      a2 = fmaxf(a2, 0.f); a3 = fmaxf(a3, 0.f);
      uint2 pkd = make_uint2(pack2(a0, a1), pack2(a2, a3));
      *(uint2*)(Xh64 + (size_t)t * 64 + 4 * sub) = pkd;
    } else {
      *(float4*)(dest + (size_t)t * 64 + 4 * sub) = make_float4(a0, a1, a2, a3);
    }
  }
}

// ---------------------------------------------------------------------------
// Phase B stage 4: out[t] = gather(bf16 Y4h[NF][128]) + bf16(ans2)@fc3.
// ---------------------------------------------------------------------------
__global__ void __launch_bounds__(256, 8) b4_stage4(
    const short* __restrict__ Xh64b, const float* __restrict__ fc3,
    const int* __restrict__ ftstart, const unsigned* __restrict__ epk,
    const uint2* __restrict__ ewh, const short* __restrict__ Y4h,
    float* __restrict__ outp) {
  int lane = threadIdx.x & 63;
  int t = blockIdx.x * 4 + (threadIdx.x >> 6);
  int s4 = ftstart[t] * 4, e4 = ftstart[t + 1] * 4;
  float m0 = 0.f, m1 = 0.f;
  for (int fq = s4 + lane; fq < e4; fq += 64) {
    int idx = fq >> 2, j = fq & 3;
    unsigned pk = epk[idx];
    uint2 wh = ewh[idx];
    int src = pk & 16383;
    int cell = (int)(pk >> 14) + (j & 1) + (j >> 1) * 8;
    unsigned wsel = (j < 2) ? wh.x : wh.y;
    float w = (j & 1) ? b2f_hi(wsel) : b2f_lo(wsel);
    unsigned mm = *(const unsigned*)(Y4h + (size_t)src * 128 + cell * 2);
    m0 = fmaf(w, b2f_lo(mm), m0);
    m1 = fmaf(w, b2f_hi(mm), m1);
  }
  {
    float a = b2fs(Xh64b[(size_t)t * 64 + lane]);
    m0 += a * fc3[lane * 2 + 0];
    m1 += a * fc3[lane * 2 + 1];
  }
#pragma unroll
  for (int off = 32; off > 0; off >>= 1) {
    m0 += __shfl_xor(m0, off, 64);
    m1 += __shfl_xor(m1, off, 64);
  }
  if (lane == 0) {
    outp[t * 2] = m0;
    outp[t * 2 + 1] = m1;
  }
}

// ---------------------------------------------------------------------------
extern "C" void kernel_launch(void* const* d_in, const int* in_sizes, int n_in,
                              void* d_out, int out_size, void* d_ws, size_t ws_size,
                              hipStream_t stream) {
  const float* fp  = (const float*)d_in[0];
  const float* bp  = (const float*)d_in[1];
  const float* ff  = (const float*)d_in[2];
  const float* bfe = (const float*)d_in[3];
  const float* sup = (const float*)d_in[4];
  const int* fi  = (const int*)d_in[5];
  const int* fj  = (const int*)d_in[6];
  const int* bfi = (const int*)d_in[7];
  const int* bb  = (const int*)d_in[8];
  const float* W0 = (const float*)d_in[9];
  const float* W1 = (const float*)d_in[10];
  const float* W2 = (const float*)d_in[11];
  const float* W3 = (const float*)d_in[12];
  const float* W4 = (const float*)d_in[13];
  const float* fc0 = (const float*)d_in[14];
  const float* fc1 = (const float*)d_in[15];
  const float* fc2 = (const float*)d_in[16];
  const float* fc3 = (const float*)d_in[17];
  float* out = (float*)d_out;

  char* w = (char*)d_ws;
  size_t off = 0;
  auto alloc = [&](size_t bytes) {
    char* p = w + off;
    off += (bytes + 255) & ~size_t(255);
    return p;
  };
  float* ans1   = (float*)alloc((size_t)NF * 64 * 4);   // fallback carry only
  float* ans2   = (float*)alloc((size_t)NF * 64 * 4);   // fallback carry only
  int* fthist  = (int*)alloc((size_t)NF * 4);
  int* bthist  = (int*)alloc((size_t)NF * 4);   // adjacent to fthist: one memset
  int* ftstart = (int*)alloc((size_t)(NF + 1) * 4);
  int* ftcur   = (int*)alloc((size_t)NF * 4);
  int* btstart = (int*)alloc((size_t)(NF + 1) * 4);
  int* btcur   = (int*)alloc((size_t)NF * 4);
  unsigned* fpk  = (unsigned*)alloc((size_t)EF * 4);
  uint2* fwh     = (uint2*)alloc((size_t)EF * 8);
  unsigned* bpk  = (unsigned*)alloc((size_t)EB * 4);
  uint2* bwh     = (uint2*)alloc((size_t)EB * 8);
  short* Xh96  = (short*)alloc((size_t)NF * 96 * 2);
  short* Xh64  = (short*)alloc((size_t)NF * 64 * 2);   // bf16 ans1
  short* Xh64b = (short*)alloc((size_t)NF * 64 * 2);   // bf16 ans2
  short* BT2 = (short*)alloc((size_t)4096 * 96 * 2);
  short* BT3 = (short*)alloc((size_t)4096 * 64 * 2);
  short* BT4 = (short*)alloc((size_t)128 * 64 * 2);
  float* W0T = (float*)alloc((size_t)8192 * 4);
  float* W1T = (float*)alloc((size_t)8192 * 4);
  char* Yreg = w + off;
  size_t avail = (ws_size > off) ? (ws_size - off) : 0;
  size_t percell = (size_t)NF * 64 * 2;
  int CC = 64;
  while (CC > 8 && (size_t)CC * percell > avail) CC >>= 1;
  int S = 64 / CC;
  short* Y   = (short*)Yreg;
  short* Y4h = (short*)Yreg;  // [NF][128] bf16, 4MB (reuses Y region)

  hipMemsetAsync(fthist, 0, (size_t)NF * 8, stream);

  prep_all<<<FBLK + BBLK + 2624, 256, 0, stream>>>(
      fi, bfi, fthist, bthist, W2, W3, W4, W0, W1, BT2, BT3, BT4, W0T, W1T);
  csr_scan2<<<2, 1024, 0, stream>>>(fthist, bthist, ftstart, ftcur, btstart, btcur);
  dual_scatter_payload<<<FBLK + BBLK, 256, 0, stream>>>(fi, fj, bfi, bb, fp, bp, sup,
                                                        ftcur, btcur, fpk, fwh, bpk, bwh);

  // Stage 1: lane-parallel fused, 1 wave/node. Emits bf16 Xh96 only.
  b1_stage1<<<NF / 4, 256, 0, stream>>>(ff, bfe, fc0, W0T, W1T,
                                        ftstart, fpk, fwh, btstart, bpk, bwh, Xh96);
  if (S == 1) {
    // Fast path: CC=64, single pass per stage.
    gemm_bf16<96><<<dim3(NF / 128, 32), 256, 0, stream>>>(Xh96, BT2, Y, 4096);
    b23<96, 0, 1><<<NF / 4, 256, 0, stream>>>(Xh96, fc1, ftstart, fpk, fwh,
                                              Y, nullptr, ans1, Xh64, 0, 64, 1, 1);
    gemm_bf16<64><<<dim3(NF / 128, 32), 256, 0, stream>>>(Xh64, BT3, Y, 4096);
    b23<64, 1, 1><<<NF / 4, 256, 0, stream>>>(Xh64, fc2, ftstart, fpk, fwh,
                                              Y, Xh64, ans2, Xh64b, 0, 64, 1, 1);
  } else {
    // Generic chunked fallback (small workspace).
    for (int c = 0; c < S; c++) {
      int c0 = c * CC;
      gemm_bf16<96><<<dim3(NF / 128, CC * 64 / 128), 256, 0, stream>>>(
          Xh96, BT2 + (size_t)c0 * 64 * 96, Y, CC * 64);
      b23<96, 0, 0><<<NF / 4, 256, 0, stream>>>(Xh96, fc1, ftstart, fpk, fwh,
                                                Y, nullptr, ans1, Xh64,
                                                c0, CC, c == 0, c == S - 1);
    }
    for (int c = 0; c < S; c++) {
      int c0 = c * CC;
      gemm_bf16<64><<<dim3(NF / 128, CC * 64 / 128), 256, 0, stream>>>(
          Xh64, BT3 + (size_t)c0 * 64 * 64, Y, CC * 64);
      b23<64, 1, 0><<<NF / 4, 256, 0, stream>>>(Xh64, fc2, ftstart, fpk, fwh,
                                                Y, Xh64, ans2, Xh64b,
                                                c0, CC, c == 0, c == S - 1);
    }
  }
  // Stage 4: W4 conv as a single MFMA GEMM [NF x 64] @ [64 x 128], then gather.
  gemm_bf16<64><<<dim3(NF / 128, 1), 256, 0, stream>>>(Xh64b, BT4, Y4h, 128);
  b4_stage4<<<NF / 4, 256, 0, stream>>>(Xh64b, fc3, ftstart, fpk, fwh, Y4h, out);
}